// Round 6
// baseline (4475.820 us; speedup 1.0000x reference)
//
#include <hip/hip_runtime.h>
#include <hip/hip_bf16.h>

// B=512, T=64, C=512, H=512, NC=96, S=26.
// Structure:
//   split_pair: batch_H -> bAh/bAl (bf16 hi/lo).
//   transpose_split x4: weights -> [N][512] bf16 hi/lo pairs.
//   gemm_pre<2>: Hproj = batch_H @ Wi (XCD-swizzled, bf16 out).
//   decode_loop (persistent, 256 blocks x 256 thr, SOFTWARE grid barrier):
//       26 steps x {P1 qh-GEMM | P2 attention | P3 z-GEMM+LSTM}.
//   gemm_pre<1>: probs = hs @ Wgen + bgen.
// All GEMMs: 3-pass bf16-split MFMA (Ahi*Bhi + Ahi*Blo + Alo*Bhi ~ fp32).
// NOTE: cooperative launch API failed silently in R5 (hs stayed poisoned);
// replaced with a monotonic-epoch agent-scope atomic barrier (what cg::sync
// lowers to on ROCm). 256 blocks / 48KB LDS / 4 waves => 1 block/CU, all
// resident by construction.

#define NSTEP 26
#define NBLK 256

typedef __bf16 bf16x8 __attribute__((ext_vector_type(8)));
typedef float f32x4 __attribute__((ext_vector_type(4)));

__device__ __forceinline__ float tanh_fast(float x) {
  float e = __expf(2.0f * x);
  return 1.0f - 2.0f / (e + 1.0f);
}
__device__ __forceinline__ float sigmoid_fast(float x) {
  return 1.0f / (1.0f + __expf(-x));
}
__device__ __forceinline__ float bflo(unsigned u) {
  union { unsigned i; float f; } c; c.i = u << 16; return c.f;
}
__device__ __forceinline__ float bfhi(unsigned u) {
  union { unsigned i; float f; } c; c.i = u & 0xffff0000u; return c.f;
}
__device__ __forceinline__ void split2(float v, __hip_bfloat16& h, __hip_bfloat16& l) {
  h = __float2bfloat16(v);
  l = __float2bfloat16(v - __bfloat162float(h));
}

// Monotonic-epoch grid barrier. Every block calls it the same number of
// times; target = (#calls so far) * NBLK. Agent-scope atomics + threadfence
// handle cross-XCD visibility (release on arrive, acquire on exit).
__device__ __forceinline__ void grid_sync(unsigned* cnt, unsigned target) {
  __syncthreads();
  if (threadIdx.x == 0) {
    __threadfence();
    __hip_atomic_fetch_add(cnt, 1u, __ATOMIC_ACQ_REL, __HIP_MEMORY_SCOPE_AGENT);
    while (__hip_atomic_load(cnt, __ATOMIC_ACQUIRE, __HIP_MEMORY_SCOPE_AGENT) < target) {}
    __threadfence();
  }
  __syncthreads();
}

// ---------------------------------------------------------------------------
// Streaming fp32 -> bf16 hi/lo split (batch_H).
// ---------------------------------------------------------------------------
__global__ __launch_bounds__(256) void split_pair(
    const float* __restrict__ src, __hip_bfloat16* __restrict__ hi,
    __hip_bfloat16* __restrict__ lo, int n8) {
  int idx = blockIdx.x * 256 + threadIdx.x;
  if (idx >= n8) return;
  const float* s = src + (size_t)idx * 8;
  float4 v0 = *(const float4*)s, v1 = *(const float4*)(s + 4);
  float vv[8] = {v0.x, v0.y, v0.z, v0.w, v1.x, v1.y, v1.z, v1.w};
  union { int4 q; __hip_bfloat16 h[8]; } uh, ul;
#pragma unroll
  for (int j = 0; j < 8; ++j) split2(vv[j], uh.h[j], ul.h[j]);
  *(int4*)&hi[(size_t)idx * 8] = uh.q;
  *(int4*)&lo[(size_t)idx * 8] = ul.q;
}

// ---------------------------------------------------------------------------
// Transpose + bf16-split weights: out[n][k] = split(src[k][n]), K = 512.
// ---------------------------------------------------------------------------
__global__ __launch_bounds__(256) void transpose_split(
    const float* __restrict__ srcA, int ldA, int NA,
    const float* __restrict__ srcB, int ldB, int Nvalid,
    __hip_bfloat16* __restrict__ hi, __hip_bfloat16* __restrict__ lo) {
  __shared__ float tile[32][33];
  const int tx = threadIdx.x, ty = threadIdx.y;
  const int n0 = blockIdx.x * 32, k0 = blockIdx.y * 32;
#pragma unroll
  for (int i = 0; i < 4; ++i) {
    int k = k0 + ty + i * 8;
    int n = n0 + tx;
    float v = 0.f;
    if (n < NA) v = srcA[(size_t)k * ldA + n];
    else if (n < Nvalid) v = srcB[(size_t)k * ldB + (n - NA)];
    tile[tx][ty + i * 8] = v;
  }
  __syncthreads();
#pragma unroll
  for (int i = 0; i < 4; ++i) {
    int n = n0 + ty + i * 8;
    int k = k0 + tx;
    float v = tile[ty + i * 8][tx];
    __hip_bfloat16 h, l;
    split2(v, h, l);
    hi[(size_t)n * 512 + k] = h;
    lo[(size_t)n * 512 + k] = l;
  }
}

// ---------------------------------------------------------------------------
// 128x64 tile, K=512, pre-split A and B. 4 waves, 3-pass MFMA.
// ---------------------------------------------------------------------------
__device__ __forceinline__ void tile128x64(
    const __hip_bfloat16* __restrict__ Ah, const __hip_bfloat16* __restrict__ Al,
    const __hip_bfloat16* __restrict__ Bh, const __hip_bfloat16* __restrict__ Bl,
    char* smem, int tid, f32x4 (&acc)[4][2]) {
  __hip_bfloat16* sAh = (__hip_bfloat16*)smem;        // 16 KB
  __hip_bfloat16* sAl = sAh + 128 * 64;               // 16 KB
  __hip_bfloat16* sBh = sAl + 128 * 64;               // 8 KB
  __hip_bfloat16* sBl = sBh + 64 * 64;                // 8 KB
  const int lane = tid & 63, wid = tid >> 6;
  const int mh = wid >> 1, nh = wid & 1;

  for (int kt = 0; kt < 8; ++kt) {
#pragma unroll
    for (int i = 0; i < 4; ++i) {
      int cid = tid + i * 256;
      int row = cid >> 3, ch = cid & 7;
      int swz = ch ^ (row & 7);
      size_t g = (size_t)row * 512 + kt * 64 + ch * 8;
      *(int4*)&sAh[row * 64 + swz * 8] = *(const int4*)&Ah[g];
      *(int4*)&sAl[row * 64 + swz * 8] = *(const int4*)&Al[g];
    }
#pragma unroll
    for (int i = 0; i < 2; ++i) {
      int cid = tid + i * 256;
      int row = cid >> 3, ch = cid & 7;
      int swz = ch ^ (row & 7);
      size_t g = (size_t)row * 512 + kt * 64 + ch * 8;
      *(int4*)&sBh[row * 64 + swz * 8] = *(const int4*)&Bh[g];
      *(int4*)&sBl[row * 64 + swz * 8] = *(const int4*)&Bl[g];
    }
    __syncthreads();

#pragma unroll
    for (int kk = 0; kk < 2; ++kk) {
      bf16x8 ahi[4], alo[4], bhi[2], blo[2];
#pragma unroll
      for (int fm = 0; fm < 4; ++fm) {
        int row = mh * 64 + fm * 16 + (lane & 15);
        int ch = kk * 4 + (lane >> 4);
        int swz = ch ^ (row & 7);
        ahi[fm] = *(const bf16x8*)&sAh[row * 64 + swz * 8];
        alo[fm] = *(const bf16x8*)&sAl[row * 64 + swz * 8];
      }
#pragma unroll
      for (int fn = 0; fn < 2; ++fn) {
        int row = nh * 32 + fn * 16 + (lane & 15);
        int ch = kk * 4 + (lane >> 4);
        int swz = ch ^ (row & 7);
        bhi[fn] = *(const bf16x8*)&sBh[row * 64 + swz * 8];
        blo[fn] = *(const bf16x8*)&sBl[row * 64 + swz * 8];
      }
#pragma unroll
      for (int fm = 0; fm < 4; ++fm)
#pragma unroll
        for (int fn = 0; fn < 2; ++fn) {
          acc[fm][fn] = __builtin_amdgcn_mfma_f32_16x16x32_bf16(ahi[fm], bhi[fn], acc[fm][fn], 0, 0, 0);
          acc[fm][fn] = __builtin_amdgcn_mfma_f32_16x16x32_bf16(ahi[fm], blo[fn], acc[fm][fn], 0, 0, 0);
          acc[fm][fn] = __builtin_amdgcn_mfma_f32_16x16x32_bf16(alo[fm], bhi[fn], acc[fm][fn], 0, 0, 0);
        }
    }
    __syncthreads();
  }
}

// ---------------------------------------------------------------------------
// Standalone pre-split GEMM. MODE 2: Hproj (XCD swizzle, bf16 out).
// MODE 1: probs (+bias, col<96, remap to [B,S,96]).
// ---------------------------------------------------------------------------
template <int MODE>
__global__ __launch_bounds__(256) void gemm_pre(
    const __hip_bfloat16* __restrict__ Ah, const __hip_bfloat16* __restrict__ Al,
    const __hip_bfloat16* __restrict__ Bh, const __hip_bfloat16* __restrict__ Bl,
    float* __restrict__ outF, __hip_bfloat16* __restrict__ out16,
    const float* __restrict__ bias) {
  __shared__ __align__(16) char smem[49152];
  const int tid = threadIdx.x;
  const int lane = tid & 63, wid = tid >> 6;
  const int mh = wid >> 1, nh = wid & 1;

  int bx = blockIdx.x, by = blockIdx.y;
  if (MODE == 2) {  // co-locate the 8 x-blocks sharing an A panel per XCD
    int lid = by * 8 + bx;
    int xcd = lid & 7, k = lid >> 3;
    by = xcd * 32 + (k >> 3);
    bx = k & 7;
  }
  const int mBase = by * 128, nBase = bx * 64;

  f32x4 acc[4][2];
#pragma unroll
  for (int fm = 0; fm < 4; ++fm)
#pragma unroll
    for (int fn = 0; fn < 2; ++fn) acc[fm][fn] = (f32x4){0.f, 0.f, 0.f, 0.f};

  tile128x64(Ah + (size_t)mBase * 512, Al + (size_t)mBase * 512,
             Bh + (size_t)nBase * 512, Bl + (size_t)nBase * 512, smem, tid, acc);

#pragma unroll
  for (int fm = 0; fm < 4; ++fm)
#pragma unroll
    for (int fn = 0; fn < 2; ++fn)
#pragma unroll
      for (int r = 0; r < 4; ++r) {
        int row = mBase + mh * 64 + fm * 16 + (lane >> 4) * 4 + r;
        int col = nBase + nh * 32 + fn * 16 + (lane & 15);
        float v = acc[fm][fn][r];
        if (MODE == 2) {
          out16[(size_t)row * 512 + col] = __float2bfloat16(v);
        } else {
          int bb = row & 511, ss = row >> 9;   // A row = s*512 + b
          if (col < 96)
            outF[((size_t)bb * NSTEP + ss) * 96 + col] = v + bias[col];
        }
      }
}

// ---------------------------------------------------------------------------
// Persistent decode loop. 256 blocks x 256 threads, software grid barrier.
// ---------------------------------------------------------------------------
struct DecodeArgs {
  const __hip_bfloat16 *W2h, *W2l;   // [2560][512]
  const __hip_bfloat16 *K1h, *K1l;   // [2048][512]
  const __hip_bfloat16 *Hp16, *bAh;  // [B*T][512]
  const float *bh, *Ws, *lstm_bias, *lstm_kernel;
  const int* text;
  float *qh, *cstate;
  __hip_bfloat16 *ctxh, *ctxl, *hsh, *hsl;
  unsigned* bar;
};

__global__ __launch_bounds__(256) void decode_loop(DecodeArgs a) {
  __shared__ __align__(16) char smem[49152];
  const int tid = threadIdx.x;
  const int lane = tid & 63, wid = tid >> 6;
  const int bid = blockIdx.x;
  unsigned bar_target = 0;

  for (int s = 0; s < NSTEP; ++s) {
    // ---- P1: qh = h_s @ [Wh | lstm_rec]  (M=512, N=2560), 160 tiles 128x64
    if (bid < 160) {
      int bx = bid % 40, by = bid / 40;
      f32x4 acc[4][2];
#pragma unroll
      for (int fm = 0; fm < 4; ++fm)
#pragma unroll
        for (int fn = 0; fn < 2; ++fn) acc[fm][fn] = (f32x4){0.f, 0.f, 0.f, 0.f};
      tile128x64(a.hsh + (size_t)s * 262144 + (size_t)by * 128 * 512,
                 a.hsl + (size_t)s * 262144 + (size_t)by * 128 * 512,
                 a.W2h + (size_t)bx * 64 * 512,
                 a.W2l + (size_t)bx * 64 * 512, smem, tid, acc);
      const int mh = wid >> 1, nh = wid & 1;
#pragma unroll
      for (int fm = 0; fm < 4; ++fm)
#pragma unroll
        for (int fn = 0; fn < 2; ++fn)
#pragma unroll
          for (int r = 0; r < 4; ++r) {
            int row = by * 128 + mh * 64 + fm * 16 + (lane >> 4) * 4 + r;
            int col = bx * 64 + nh * 32 + fn * 16 + (lane & 15);
            a.qh[(size_t)row * 2560 + col] = acc[fm][fn][r];
          }
    }
    bar_target += NBLK;
    grid_sync(a.bar, bar_target);

    // ---- P2: attention, 2 batch rows per block
    {
      float* qs = (float*)smem;         // 512
      float* wss = qs + 512;            // 512
      float* es = wss + 512;            // 64
      float* als = es + 64;             // 64
      for (int r = 0; r < 2; ++r) {
        int b = bid * 2 + r;
        qs[tid] = a.qh[(size_t)b * 2560 + tid] + a.bh[tid];
        qs[tid + 256] = a.qh[(size_t)b * 2560 + 256 + tid] + a.bh[256 + tid];
        wss[tid] = a.Ws[tid];
        wss[tid + 256] = a.Ws[tid + 256];
        __syncthreads();
        float qv[8], wv[8];
#pragma unroll
        for (int j = 0; j < 8; ++j) {
          qv[j] = qs[lane * 8 + j];
          wv[j] = wss[lane * 8 + j];
        }
        const __hip_bfloat16* Hp = a.Hp16 + (size_t)b * 32768;
#pragma unroll
        for (int i = 0; i < 16; ++i) {
          int t = wid * 16 + i;
          uint4 p = *(const uint4*)(Hp + (size_t)t * 512 + lane * 8);
          float sum = wv[0] * tanh_fast(bflo(p.x) + qv[0]) + wv[1] * tanh_fast(bfhi(p.x) + qv[1]) +
                      wv[2] * tanh_fast(bflo(p.y) + qv[2]) + wv[3] * tanh_fast(bfhi(p.y) + qv[3]) +
                      wv[4] * tanh_fast(bflo(p.z) + qv[4]) + wv[5] * tanh_fast(bfhi(p.z) + qv[5]) +
                      wv[6] * tanh_fast(bflo(p.w) + qv[6]) + wv[7] * tanh_fast(bfhi(p.w) + qv[7]);
#pragma unroll
          for (int off = 32; off; off >>= 1) sum += __shfl_xor(sum, off);
          if (lane == 0) es[t] = sum;
        }
        __syncthreads();
        if (wid == 0) {
          float e = es[lane];
          float m = e;
#pragma unroll
          for (int off = 32; off; off >>= 1) m = fmaxf(m, __shfl_xor(m, off));
          float p = __expf(e - m);
          float sm = p;
#pragma unroll
          for (int off = 32; off; off >>= 1) sm += __shfl_xor(sm, off);
          als[lane] = p / sm;
        }
        __syncthreads();
        // ctx: thread owns channels 2*tid, 2*tid+1
        const unsigned* Bp = (const unsigned*)(a.bAh + (size_t)b * 32768);
        float sx = 0.f, sy = 0.f;
#pragma unroll 8
        for (int t = 0; t < 64; ++t) {
          unsigned u = Bp[t * 256 + tid];
          float al = als[t];
          sx += al * bflo(u);
          sy += al * bfhi(u);
        }
        union { __hip_bfloat16 h[2]; unsigned u; } ph, pl;
        split2(sx, ph.h[0], pl.h[0]);
        split2(sy, ph.h[1], pl.h[1]);
        ((unsigned*)a.ctxh)[(size_t)b * 256 + tid] = ph.u;
        ((unsigned*)a.ctxl)[(size_t)b * 256 + tid] = pl.u;
        __syncthreads();
      }
    }
    bar_target += NBLK;
    grid_sync(a.bar, bar_target);

    // ---- P3: z = ctx @ K1 (gate-strided cols) + fused LSTM. 256 tiles 64x64.
    {
      const int j0 = (bid & 31) * 16, mBase = (bid >> 5) * 64;
      __hip_bfloat16* sAh = (__hip_bfloat16*)smem;     // 8 KB
      __hip_bfloat16* sAl = sAh + 64 * 64;             // 8 KB
      __hip_bfloat16* sBh = sAl + 64 * 64;             // 8 KB
      __hip_bfloat16* sBl = sBh + 64 * 64;             // 8 KB
      float* zl = (float*)(smem + 32768);              // 16 KB
      const int wm = wid >> 1, wl = wid & 1;

      f32x4 acc[2][2];
#pragma unroll
      for (int fm = 0; fm < 2; ++fm)
#pragma unroll
        for (int fl = 0; fl < 2; ++fl) acc[fm][fl] = (f32x4){0.f, 0.f, 0.f, 0.f};

      for (int kt = 0; kt < 8; ++kt) {
#pragma unroll
        for (int i = 0; i < 2; ++i) {
          int cid = tid + i * 256;
          int row = cid >> 3, ch = cid & 7;
          int swz = ch ^ (row & 7);
          size_t g = (size_t)(mBase + row) * 512 + kt * 64 + ch * 8;
          *(int4*)&sAh[row * 64 + swz * 8] = *(const int4*)&a.ctxh[g];
          *(int4*)&sAl[row * 64 + swz * 8] = *(const int4*)&a.ctxl[g];
        }
#pragma unroll
        for (int i = 0; i < 2; ++i) {
          int cid = tid + i * 256;
          int lr = cid >> 3, ch = cid & 7;
          int gate = lr >> 4, jj = lr & 15;
          int swz = ch ^ (lr & 7);
          size_t g = (size_t)(gate * 512 + j0 + jj) * 512 + kt * 64 + ch * 8;
          *(int4*)&sBh[lr * 64 + swz * 8] = *(const int4*)&a.K1h[g];
          *(int4*)&sBl[lr * 64 + swz * 8] = *(const int4*)&a.K1l[g];
        }
        __syncthreads();

#pragma unroll
        for (int kk = 0; kk < 2; ++kk) {
          bf16x8 ahi[2], alo[2], bhi[2], blo[2];
#pragma unroll
          for (int fm = 0; fm < 2; ++fm) {
            int row = wm * 32 + fm * 16 + (lane & 15);
            int ch = kk * 4 + (lane >> 4);
            int swz = ch ^ (row & 7);
            ahi[fm] = *(const bf16x8*)&sAh[row * 64 + swz * 8];
            alo[fm] = *(const bf16x8*)&sAl[row * 64 + swz * 8];
          }
#pragma unroll
          for (int fl = 0; fl < 2; ++fl) {
            int lr = wl * 32 + fl * 16 + (lane & 15);
            int ch = kk * 4 + (lane >> 4);
            int swz = ch ^ (lr & 7);
            bhi[fl] = *(const bf16x8*)&sBh[lr * 64 + swz * 8];
            blo[fl] = *(const bf16x8*)&sBl[lr * 64 + swz * 8];
          }
#pragma unroll
          for (int fm = 0; fm < 2; ++fm)
#pragma unroll
            for (int fl = 0; fl < 2; ++fl) {
              acc[fm][fl] = __builtin_amdgcn_mfma_f32_16x16x32_bf16(ahi[fm], bhi[fl], acc[fm][fl], 0, 0, 0);
              acc[fm][fl] = __builtin_amdgcn_mfma_f32_16x16x32_bf16(ahi[fm], blo[fl], acc[fm][fl], 0, 0, 0);
              acc[fm][fl] = __builtin_amdgcn_mfma_f32_16x16x32_bf16(alo[fm], bhi[fl], acc[fm][fl], 0, 0, 0);
            }
        }
        __syncthreads();
      }

      // z into LDS (separate region; no alias with staging)
#pragma unroll
      for (int fm = 0; fm < 2; ++fm)
#pragma unroll
        for (int fl = 0; fl < 2; ++fl)
#pragma unroll
          for (int r = 0; r < 4; ++r) {
            int row = wm * 32 + fm * 16 + (lane >> 4) * 4 + r;
            int lr = wl * 32 + fl * 16 + (lane & 15);
            zl[row * 64 + lr] = acc[fm][fl][r];
          }
      __syncthreads();

      // LSTM pointwise: 64 rows x 16 j
#pragma unroll
      for (int i = 0; i < 4; ++i) {
        int p = tid + i * 256;
        int row = p >> 4, j = p & 15;
        int b = mBase + row, jc = j0 + j;
        int chr = a.text[b * NSTEP + s];
        const float* crow = a.lstm_kernel + (size_t)(512 + chr) * 2048;
        const float* hrec = a.qh + (size_t)b * 2560 + 512;
        float g4[4];
#pragma unroll
        for (int g = 0; g < 4; ++g) {
          int col = g * 512 + jc;
          g4[g] = zl[row * 64 + g * 16 + j] + hrec[col] + a.lstm_bias[col] + crow[col];
        }
        float iv = sigmoid_fast(g4[0]);
        float fv = sigmoid_fast(g4[1]);
        float gv = tanh_fast(g4[2]);
        float ov = sigmoid_fast(g4[3]);
        size_t gi = (size_t)b * 512 + jc;
        float c = fv * a.cstate[gi] + iv * gv;
        a.cstate[gi] = c;
        float hv = ov * tanh_fast(c);
        __hip_bfloat16 hh, hl;
        split2(hv, hh, hl);
        a.hsh[(size_t)(s + 1) * 262144 + gi] = hh;
        a.hsl[(size_t)(s + 1) * 262144 + gi] = hl;
      }
    }
    bar_target += NBLK;
    grid_sync(a.bar, bar_target);
  }
}

// ---------------------------------------------------------------------------
extern "C" void kernel_launch(void* const* d_in, const int* in_sizes, int n_in,
                              void* d_out, int out_size, void* d_ws, size_t ws_size,
                              hipStream_t stream) {
  (void)in_sizes; (void)n_in; (void)out_size; (void)ws_size;
  const float* batch_H = (const float*)d_in[0];
  const int* text = (const int*)d_in[1];
  const float* Wi = (const float*)d_in[3];
  const float* Wh = (const float*)d_in[4];
  const float* bh = (const float*)d_in[5];
  const float* Ws = (const float*)d_in[6];
  const float* lstm_kernel = (const float*)d_in[7];
  const float* lstm_rec = (const float*)d_in[8];
  const float* lstm_bias = (const float*)d_in[9];
  const float* Wgen = (const float*)d_in[10];
  const float* bgen = (const float*)d_in[11];
  float* out = (float*)d_out;

  char* w = (char*)d_ws;
  auto alloc = [&](size_t bytes) {
    char* p = w;
    w += (bytes + 255) & ~(size_t)255;
    return p;
  };
  const size_t NE = 32768ull * 512;                      // batch_H elems
  __hip_bfloat16* bAh = (__hip_bfloat16*)alloc(NE * 2);  // 33.5 MB
  char* bAl_region = alloc(NE * 2);                      // 33.5 MB (dead after Hproj)
  __hip_bfloat16* bAl = (__hip_bfloat16*)bAl_region;
  __hip_bfloat16* Hp16 = (__hip_bfloat16*)alloc(NE * 2); // 33.5 MB
  __hip_bfloat16* WiT_h = (__hip_bfloat16*)alloc(512ull * 512 * 2);
  __hip_bfloat16* WiT_l = (__hip_bfloat16*)alloc(512ull * 512 * 2);
  __hip_bfloat16* W2T_h = (__hip_bfloat16*)alloc(2560ull * 512 * 2);
  __hip_bfloat16* W2T_l = (__hip_bfloat16*)alloc(2560ull * 512 * 2);
  __hip_bfloat16* K1T_h = (__hip_bfloat16*)alloc(2048ull * 512 * 2);
  __hip_bfloat16* K1T_l = (__hip_bfloat16*)alloc(2048ull * 512 * 2);
  __hip_bfloat16* WgT_h = (__hip_bfloat16*)alloc(128ull * 512 * 2);
  __hip_bfloat16* WgT_l = (__hip_bfloat16*)alloc(128ull * 512 * 2);
  float* qh = (float*)alloc(512ull * 2560 * 4);          // 5.2 MB
  float* cstate = (float*)alloc(512ull * 512 * 4);       // 1 MB
  unsigned* bar = (unsigned*)alloc(256);
  // hs/ctx pairs alias the dead bAl region (Hproj finishes before the memsets)
  __hip_bfloat16* hsh = (__hip_bfloat16*)bAl_region;                       // 14.2 MB
  __hip_bfloat16* hsl = (__hip_bfloat16*)(bAl_region + 27ull * 262144 * 2);// 14.2 MB
  __hip_bfloat16* ctxh = (__hip_bfloat16*)(bAl_region + 2ull * 27 * 262144 * 2);
  __hip_bfloat16* ctxl = ctxh + 512ull * 512;

  // Stage 1: splits + weight prep (independent of each other)
  split_pair<<<dim3(8192), 256, 0, stream>>>(batch_H, bAh, bAl, (int)(NE / 8));
  dim3 tb(32, 8, 1);
  transpose_split<<<dim3(16, 16), tb, 0, stream>>>(Wi, 512, 512, Wi, 512, 512, WiT_h, WiT_l);
  transpose_split<<<dim3(80, 16), tb, 0, stream>>>(Wh, 512, 512, lstm_rec, 2048, 2560, W2T_h, W2T_l);
  transpose_split<<<dim3(64, 16), tb, 0, stream>>>(lstm_kernel, 2048, 2048, lstm_kernel, 2048, 2048, K1T_h, K1T_l);
  transpose_split<<<dim3(4, 16), tb, 0, stream>>>(Wgen, 96, 96, Wgen, 96, 96, WgT_h, WgT_l);

  // Stage 2: Hproj (consumes bAl; last use of that region)
  gemm_pre<2><<<dim3(8, 256), 256, 0, stream>>>(bAh, bAl, WiT_h, WiT_l,
                                                nullptr, Hp16, nullptr);

  // Stage 3: init recurrent state + barrier (aliases the now-dead bAl region)
  hipMemsetAsync(hsh, 0, 262144ull * 2, stream);   // h_{-1} hi = 0
  hipMemsetAsync(hsl, 0, 262144ull * 2, stream);   // h_{-1} lo = 0
  hipMemsetAsync(cstate, 0, 512ull * 512 * 4, stream);
  hipMemsetAsync(bar, 0, 256, stream);

  // Stage 4: persistent decode loop (plain launch + software grid barrier)
  DecodeArgs args;
  args.W2h = W2T_h; args.W2l = W2T_l;
  args.K1h = K1T_h; args.K1l = K1T_l;
  args.Hp16 = Hp16; args.bAh = bAh;
  args.bh = bh; args.Ws = Ws; args.lstm_bias = lstm_bias; args.lstm_kernel = lstm_kernel;
  args.text = text;
  args.qh = qh; args.cstate = cstate;
  args.ctxh = ctxh; args.ctxl = ctxl; args.hsh = hsh; args.hsl = hsl;
  args.bar = bar;
  decode_loop<<<dim3(NBLK), 256, 0, stream>>>(args);

  // Stage 5: probs = hs @ Wgen + bgen : M=13312, N=128 (96 valid)
  gemm_pre<1><<<dim3(2, 104), 256, 0, stream>>>(hsh + 262144, hsl + 262144,
                                                WgT_h, WgT_l, out, nullptr, bgen);
}

// Round 7
// 3922.456 us; speedup vs baseline: 1.1411x; 1.1411x over previous
//
#include <hip/hip_runtime.h>
#include <hip/hip_bf16.h>

// B=512, T=64, C=512, H=512, NC=96, S=26.
//   split_pair: batch_H -> bAh/bAl (bf16 hi/lo).
//   transpose_split x4: weights -> [N][512] bf16 hi/lo pairs.
//   gemm_pre<2>: Hproj = batch_H @ Wi (XCD-swizzled, bf16 out).
//   decode_loop (persistent, 256 blocks x 512 thr, software grid barrier
//     with s_sleep backoff): 26 x {P1 qh-GEMM | P2 attn (2 rows parallel)
//     | P3 z-GEMM+LSTM (all blocks)}.
//   gemm_pre<1>: probs = hs @ Wgen + bgen.
// All GEMMs: 3-pass bf16-split MFMA (~fp32 precision).

#define NSTEP 26
#define NBLK 256

typedef __bf16 bf16x8 __attribute__((ext_vector_type(8)));
typedef float f32x4 __attribute__((ext_vector_type(4)));

__device__ __forceinline__ float tanh_fast(float x) {
  float e = __expf(2.0f * x);
  return 1.0f - 2.0f / (e + 1.0f);
}
__device__ __forceinline__ float sigmoid_fast(float x) {
  return 1.0f / (1.0f + __expf(-x));
}
__device__ __forceinline__ float bflo(unsigned u) {
  union { unsigned i; float f; } c; c.i = u << 16; return c.f;
}
__device__ __forceinline__ float bfhi(unsigned u) {
  union { unsigned i; float f; } c; c.i = u & 0xffff0000u; return c.f;
}
__device__ __forceinline__ void split2(float v, __hip_bfloat16& h, __hip_bfloat16& l) {
  h = __float2bfloat16(v);
  l = __float2bfloat16(v - __bfloat162float(h));
}

// Monotonic-epoch grid barrier, s_sleep backoff in the spin.
__device__ __forceinline__ void grid_sync(unsigned* cnt, unsigned target) {
  __syncthreads();
  if (threadIdx.x == 0) {
    __threadfence();
    __hip_atomic_fetch_add(cnt, 1u, __ATOMIC_ACQ_REL, __HIP_MEMORY_SCOPE_AGENT);
    while (__hip_atomic_load(cnt, __ATOMIC_ACQUIRE, __HIP_MEMORY_SCOPE_AGENT) < target)
      __builtin_amdgcn_s_sleep(1);
    __threadfence();
  }
  __syncthreads();
}

// ---------------------------------------------------------------------------
__global__ __launch_bounds__(256) void split_pair(
    const float* __restrict__ src, __hip_bfloat16* __restrict__ hi,
    __hip_bfloat16* __restrict__ lo, int n8) {
  int idx = blockIdx.x * 256 + threadIdx.x;
  if (idx >= n8) return;
  const float* s = src + (size_t)idx * 8;
  float4 v0 = *(const float4*)s, v1 = *(const float4*)(s + 4);
  float vv[8] = {v0.x, v0.y, v0.z, v0.w, v1.x, v1.y, v1.z, v1.w};
  union { int4 q; __hip_bfloat16 h[8]; } uh, ul;
#pragma unroll
  for (int j = 0; j < 8; ++j) split2(vv[j], uh.h[j], ul.h[j]);
  *(int4*)&hi[(size_t)idx * 8] = uh.q;
  *(int4*)&lo[(size_t)idx * 8] = ul.q;
}

// ---------------------------------------------------------------------------
__global__ __launch_bounds__(256) void transpose_split(
    const float* __restrict__ srcA, int ldA, int NA,
    const float* __restrict__ srcB, int ldB, int Nvalid,
    __hip_bfloat16* __restrict__ hi, __hip_bfloat16* __restrict__ lo) {
  __shared__ float tile[32][33];
  const int tx = threadIdx.x, ty = threadIdx.y;
  const int n0 = blockIdx.x * 32, k0 = blockIdx.y * 32;
#pragma unroll
  for (int i = 0; i < 4; ++i) {
    int k = k0 + ty + i * 8;
    int n = n0 + tx;
    float v = 0.f;
    if (n < NA) v = srcA[(size_t)k * ldA + n];
    else if (n < Nvalid) v = srcB[(size_t)k * ldB + (n - NA)];
    tile[tx][ty + i * 8] = v;
  }
  __syncthreads();
#pragma unroll
  for (int i = 0; i < 4; ++i) {
    int n = n0 + ty + i * 8;
    int k = k0 + tx;
    float v = tile[ty + i * 8][tx];
    __hip_bfloat16 h, l;
    split2(v, h, l);
    hi[(size_t)n * 512 + k] = h;
    lo[(size_t)n * 512 + k] = l;
  }
}

// ---------------------------------------------------------------------------
// 128x64 tile helper for the 256-thread pre/post GEMMs.
// ---------------------------------------------------------------------------
__device__ __forceinline__ void tile128x64(
    const __hip_bfloat16* __restrict__ Ah, const __hip_bfloat16* __restrict__ Al,
    const __hip_bfloat16* __restrict__ Bh, const __hip_bfloat16* __restrict__ Bl,
    char* smem, int tid, f32x4 (&acc)[4][2]) {
  __hip_bfloat16* sAh = (__hip_bfloat16*)smem;
  __hip_bfloat16* sAl = sAh + 128 * 64;
  __hip_bfloat16* sBh = sAl + 128 * 64;
  __hip_bfloat16* sBl = sBh + 64 * 64;
  const int lane = tid & 63, wid = tid >> 6;
  const int mh = wid >> 1, nh = wid & 1;

  for (int kt = 0; kt < 8; ++kt) {
#pragma unroll
    for (int i = 0; i < 4; ++i) {
      int cid = tid + i * 256;
      int row = cid >> 3, ch = cid & 7;
      int swz = ch ^ (row & 7);
      size_t g = (size_t)row * 512 + kt * 64 + ch * 8;
      *(int4*)&sAh[row * 64 + swz * 8] = *(const int4*)&Ah[g];
      *(int4*)&sAl[row * 64 + swz * 8] = *(const int4*)&Al[g];
    }
#pragma unroll
    for (int i = 0; i < 2; ++i) {
      int cid = tid + i * 256;
      int row = cid >> 3, ch = cid & 7;
      int swz = ch ^ (row & 7);
      size_t g = (size_t)row * 512 + kt * 64 + ch * 8;
      *(int4*)&sBh[row * 64 + swz * 8] = *(const int4*)&Bh[g];
      *(int4*)&sBl[row * 64 + swz * 8] = *(const int4*)&Bl[g];
    }
    __syncthreads();

#pragma unroll
    for (int kk = 0; kk < 2; ++kk) {
      bf16x8 ahi[4], alo[4], bhi[2], blo[2];
#pragma unroll
      for (int fm = 0; fm < 4; ++fm) {
        int row = mh * 64 + fm * 16 + (lane & 15);
        int ch = kk * 4 + (lane >> 4);
        int swz = ch ^ (row & 7);
        ahi[fm] = *(const bf16x8*)&sAh[row * 64 + swz * 8];
        alo[fm] = *(const bf16x8*)&sAl[row * 64 + swz * 8];
      }
#pragma unroll
      for (int fn = 0; fn < 2; ++fn) {
        int row = nh * 32 + fn * 16 + (lane & 15);
        int ch = kk * 4 + (lane >> 4);
        int swz = ch ^ (row & 7);
        bhi[fn] = *(const bf16x8*)&sBh[row * 64 + swz * 8];
        blo[fn] = *(const bf16x8*)&sBl[row * 64 + swz * 8];
      }
#pragma unroll
      for (int fm = 0; fm < 4; ++fm)
#pragma unroll
        for (int fn = 0; fn < 2; ++fn) {
          acc[fm][fn] = __builtin_amdgcn_mfma_f32_16x16x32_bf16(ahi[fm], bhi[fn], acc[fm][fn], 0, 0, 0);
          acc[fm][fn] = __builtin_amdgcn_mfma_f32_16x16x32_bf16(ahi[fm], blo[fn], acc[fm][fn], 0, 0, 0);
          acc[fm][fn] = __builtin_amdgcn_mfma_f32_16x16x32_bf16(alo[fm], bhi[fn], acc[fm][fn], 0, 0, 0);
        }
    }
    __syncthreads();
  }
}

// ---------------------------------------------------------------------------
template <int MODE>
__global__ __launch_bounds__(256) void gemm_pre(
    const __hip_bfloat16* __restrict__ Ah, const __hip_bfloat16* __restrict__ Al,
    const __hip_bfloat16* __restrict__ Bh, const __hip_bfloat16* __restrict__ Bl,
    float* __restrict__ outF, __hip_bfloat16* __restrict__ out16,
    const float* __restrict__ bias) {
  __shared__ __align__(16) char smem[49152];
  const int tid = threadIdx.x;
  const int lane = tid & 63, wid = tid >> 6;
  const int mh = wid >> 1, nh = wid & 1;

  int bx = blockIdx.x, by = blockIdx.y;
  if (MODE == 2) {
    int lid = by * 8 + bx;
    int xcd = lid & 7, k = lid >> 3;
    by = xcd * 32 + (k >> 3);
    bx = k & 7;
  }
  const int mBase = by * 128, nBase = bx * 64;

  f32x4 acc[4][2];
#pragma unroll
  for (int fm = 0; fm < 4; ++fm)
#pragma unroll
    for (int fn = 0; fn < 2; ++fn) acc[fm][fn] = (f32x4){0.f, 0.f, 0.f, 0.f};

  tile128x64(Ah + (size_t)mBase * 512, Al + (size_t)mBase * 512,
             Bh + (size_t)nBase * 512, Bl + (size_t)nBase * 512, smem, tid, acc);

#pragma unroll
  for (int fm = 0; fm < 4; ++fm)
#pragma unroll
    for (int fn = 0; fn < 2; ++fn)
#pragma unroll
      for (int r = 0; r < 4; ++r) {
        int row = mBase + mh * 64 + fm * 16 + (lane >> 4) * 4 + r;
        int col = nBase + nh * 32 + fn * 16 + (lane & 15);
        float v = acc[fm][fn][r];
        if (MODE == 2) {
          out16[(size_t)row * 512 + col] = __float2bfloat16(v);
        } else {
          int bb = row & 511, ss = row >> 9;   // A row = s*512 + b
          if (col < 96)
            outF[((size_t)bb * NSTEP + ss) * 96 + col] = v + bias[col];
        }
      }
}

// ---------------------------------------------------------------------------
// Persistent decode loop. 256 blocks x 512 threads (8 waves/CU).
// ---------------------------------------------------------------------------
struct DecodeArgs {
  const __hip_bfloat16 *W2h, *W2l;   // [2560][512]
  const __hip_bfloat16 *K1h, *K1l;   // [2048][512]
  const __hip_bfloat16 *Hp16, *bAh;  // [B*T][512]
  const float *bh, *Ws, *lstm_bias, *lstm_kernel;
  const int* text;
  float *qh, *cstate;
  __hip_bfloat16 *ctxh, *ctxl, *hsh, *hsl;
  unsigned* bar;
};

__global__ __launch_bounds__(512) void decode_loop(DecodeArgs a) {
  __shared__ __align__(16) char smem[49152];
  const int tid = threadIdx.x;
  const int lane = tid & 63, wid = tid >> 6;
  const int bid = blockIdx.x;
  unsigned bar_target = 0;

  for (int s = 0; s < NSTEP; ++s) {
    // ---- P1: qh = h_s @ [Wh | lstm_rec]  (M=512,N=2560). 160 blocks,
    // tile 128x64, 8 waves = 4m x 2n of 32x32 wave-tiles.
    if (bid < 160) {
      const int bx = bid % 40, by = bid / 40;
      __hip_bfloat16* sAh = (__hip_bfloat16*)smem;   // 16 KB
      __hip_bfloat16* sAl = sAh + 128 * 64;          // 16 KB
      __hip_bfloat16* sBh = sAl + 128 * 64;          // 8 KB
      __hip_bfloat16* sBl = sBh + 64 * 64;           // 8 KB
      const __hip_bfloat16* Ah = a.hsh + (size_t)s * 262144 + (size_t)by * 128 * 512;
      const __hip_bfloat16* Al = a.hsl + (size_t)s * 262144 + (size_t)by * 128 * 512;
      const __hip_bfloat16* Bh = a.W2h + (size_t)bx * 64 * 512;
      const __hip_bfloat16* Bl = a.W2l + (size_t)bx * 64 * 512;
      const int mh = wid >> 1, nh = wid & 1;

      f32x4 acc[2][2];
#pragma unroll
      for (int fm = 0; fm < 2; ++fm)
#pragma unroll
        for (int fn = 0; fn < 2; ++fn) acc[fm][fn] = (f32x4){0.f, 0.f, 0.f, 0.f};

      for (int kt = 0; kt < 8; ++kt) {
#pragma unroll
        for (int i = 0; i < 2; ++i) {
          int cid = tid + i * 512;
          int row = cid >> 3, ch = cid & 7;
          int swz = ch ^ (row & 7);
          size_t g = (size_t)row * 512 + kt * 64 + ch * 8;
          *(int4*)&sAh[row * 64 + swz * 8] = *(const int4*)&Ah[g];
          *(int4*)&sAl[row * 64 + swz * 8] = *(const int4*)&Al[g];
        }
        {
          int row = tid >> 3, ch = tid & 7;
          int swz = ch ^ (row & 7);
          size_t g = (size_t)row * 512 + kt * 64 + ch * 8;
          *(int4*)&sBh[row * 64 + swz * 8] = *(const int4*)&Bh[g];
          *(int4*)&sBl[row * 64 + swz * 8] = *(const int4*)&Bl[g];
        }
        __syncthreads();

#pragma unroll
        for (int kk = 0; kk < 2; ++kk) {
          bf16x8 ahi[2], alo[2], bhi[2], blo[2];
#pragma unroll
          for (int fm = 0; fm < 2; ++fm) {
            int row = mh * 32 + fm * 16 + (lane & 15);
            int ch = kk * 4 + (lane >> 4);
            int swz = ch ^ (row & 7);
            ahi[fm] = *(const bf16x8*)&sAh[row * 64 + swz * 8];
            alo[fm] = *(const bf16x8*)&sAl[row * 64 + swz * 8];
          }
#pragma unroll
          for (int fn = 0; fn < 2; ++fn) {
            int row = nh * 32 + fn * 16 + (lane & 15);
            int ch = kk * 4 + (lane >> 4);
            int swz = ch ^ (row & 7);
            bhi[fn] = *(const bf16x8*)&sBh[row * 64 + swz * 8];
            blo[fn] = *(const bf16x8*)&sBl[row * 64 + swz * 8];
          }
#pragma unroll
          for (int fm = 0; fm < 2; ++fm)
#pragma unroll
            for (int fn = 0; fn < 2; ++fn) {
              acc[fm][fn] = __builtin_amdgcn_mfma_f32_16x16x32_bf16(ahi[fm], bhi[fn], acc[fm][fn], 0, 0, 0);
              acc[fm][fn] = __builtin_amdgcn_mfma_f32_16x16x32_bf16(ahi[fm], blo[fn], acc[fm][fn], 0, 0, 0);
              acc[fm][fn] = __builtin_amdgcn_mfma_f32_16x16x32_bf16(alo[fm], bhi[fn], acc[fm][fn], 0, 0, 0);
            }
        }
        __syncthreads();
      }
#pragma unroll
      for (int fm = 0; fm < 2; ++fm)
#pragma unroll
        for (int fn = 0; fn < 2; ++fn)
#pragma unroll
          for (int r = 0; r < 4; ++r) {
            int row = by * 128 + mh * 32 + fm * 16 + (lane >> 4) * 4 + r;
            int col = bx * 64 + nh * 32 + fn * 16 + (lane & 15);
            a.qh[(size_t)row * 2560 + col] = acc[fm][fn][r];
          }
    }
    bar_target += NBLK;
    grid_sync(a.bar, bar_target);

    // ---- P2: attention. 2 rows per block, both in PARALLEL:
    // waves 0-3 -> row 2*bid, waves 4-7 -> row 2*bid+1.
    {
      const int half = tid >> 8;      // 0/1
      const int ltid = tid & 255;
      const int w4 = wid & 3;
      const int b = bid * 2 + half;
      float* es = (float*)smem;       // es[2][64]
      float* als = es + 128;          // als[2][64]

      float qv[8], wv[8];
      {
        const float* qp = a.qh + (size_t)b * 2560 + lane * 8;
        const float* bp = a.bh + lane * 8;
        const float* wp = a.Ws + lane * 8;
        float4 q0 = *(const float4*)qp, q1 = *(const float4*)(qp + 4);
        float4 h0 = *(const float4*)bp, h1 = *(const float4*)(bp + 4);
        float4 w0 = *(const float4*)wp, w1 = *(const float4*)(wp + 4);
        qv[0] = q0.x + h0.x; qv[1] = q0.y + h0.y; qv[2] = q0.z + h0.z; qv[3] = q0.w + h0.w;
        qv[4] = q1.x + h1.x; qv[5] = q1.y + h1.y; qv[6] = q1.z + h1.z; qv[7] = q1.w + h1.w;
        wv[0] = w0.x; wv[1] = w0.y; wv[2] = w0.z; wv[3] = w0.w;
        wv[4] = w1.x; wv[5] = w1.y; wv[6] = w1.z; wv[7] = w1.w;
      }
      const __hip_bfloat16* Hp = a.Hp16 + (size_t)b * 32768;
#pragma unroll
      for (int i = 0; i < 16; ++i) {
        int t = w4 * 16 + i;
        uint4 p = *(const uint4*)(Hp + (size_t)t * 512 + lane * 8);
        float sum = wv[0] * tanh_fast(bflo(p.x) + qv[0]) + wv[1] * tanh_fast(bfhi(p.x) + qv[1]) +
                    wv[2] * tanh_fast(bflo(p.y) + qv[2]) + wv[3] * tanh_fast(bfhi(p.y) + qv[3]) +
                    wv[4] * tanh_fast(bflo(p.z) + qv[4]) + wv[5] * tanh_fast(bfhi(p.z) + qv[5]) +
                    wv[6] * tanh_fast(bflo(p.w) + qv[6]) + wv[7] * tanh_fast(bfhi(p.w) + qv[7]);
#pragma unroll
        for (int off = 32; off; off >>= 1) sum += __shfl_xor(sum, off);
        if (lane == 0) es[half * 64 + t] = sum;
      }
      __syncthreads();
      if (w4 == 0) {   // wid==0 (half 0) and wid==4 (half 1)
        float e = es[half * 64 + lane];
        float m = e;
#pragma unroll
        for (int off = 32; off; off >>= 1) m = fmaxf(m, __shfl_xor(m, off));
        float p = __expf(e - m);
        float sm = p;
#pragma unroll
        for (int off = 32; off; off >>= 1) sm += __shfl_xor(sm, off);
        als[half * 64 + lane] = p / sm;
      }
      __syncthreads();
      const unsigned* Bp = (const unsigned*)(a.bAh + (size_t)b * 32768);
      float sx = 0.f, sy = 0.f;
#pragma unroll 8
      for (int t = 0; t < 64; ++t) {
        unsigned u = Bp[t * 256 + ltid];
        float al = als[half * 64 + t];
        sx += al * bflo(u);
        sy += al * bfhi(u);
      }
      union { __hip_bfloat16 h[2]; unsigned u; } ph, pl;
      split2(sx, ph.h[0], pl.h[0]);
      split2(sy, ph.h[1], pl.h[1]);
      ((unsigned*)a.ctxh)[(size_t)b * 256 + ltid] = ph.u;
      ((unsigned*)a.ctxl)[(size_t)b * 256 + ltid] = pl.u;
    }
    bar_target += NBLK;
    grid_sync(a.bar, bar_target);

    // ---- P3: z = ctx @ K1 + fused LSTM. ALL 256 blocks:
    // tile 32 rows x 32 j (=128 gate-strided cols). 8 waves = 2m x 4n
    // of 16x32 wave-tiles.
    {
      const int mpanel = bid >> 4, jchunk = bid & 15;
      const int mBase = mpanel * 32, j0 = jchunk * 32;
      __hip_bfloat16* sAh = (__hip_bfloat16*)smem;     // 4 KB
      __hip_bfloat16* sAl = sAh + 32 * 64;             // 4 KB
      __hip_bfloat16* sBh = sAl + 32 * 64;             // 16 KB
      __hip_bfloat16* sBl = sBh + 128 * 64;            // 16 KB
      float* zl = (float*)(smem + 8192);               // 16 KB, overlays sBh
      const int wm = wid >> 2, wn = wid & 3;

      f32x4 acc2[2];
      acc2[0] = (f32x4){0.f, 0.f, 0.f, 0.f};
      acc2[1] = (f32x4){0.f, 0.f, 0.f, 0.f};

      for (int kt = 0; kt < 8; ++kt) {
        if (tid < 256) {
          int row = tid >> 3, ch = tid & 7;
          int swz = ch ^ (row & 7);
          size_t g = (size_t)(mBase + row) * 512 + kt * 64 + ch * 8;
          *(int4*)&sAh[row * 64 + swz * 8] = *(const int4*)&a.ctxh[g];
          *(int4*)&sAl[row * 64 + swz * 8] = *(const int4*)&a.ctxl[g];
        }
#pragma unroll
        for (int i = 0; i < 2; ++i) {
          int cid = tid + i * 512;
          int lr = cid >> 3, ch = cid & 7;
          int gate = lr >> 5, jj = lr & 31;
          int swz = ch ^ (lr & 7);
          size_t g = (size_t)(gate * 512 + j0 + jj) * 512 + kt * 64 + ch * 8;
          *(int4*)&sBh[lr * 64 + swz * 8] = *(const int4*)&a.K1h[g];
          *(int4*)&sBl[lr * 64 + swz * 8] = *(const int4*)&a.K1l[g];
        }
        __syncthreads();

#pragma unroll
        for (int kk = 0; kk < 2; ++kk) {
          bf16x8 ahi, alo, bhi[2], blo[2];
          {
            int row = wm * 16 + (lane & 15);
            int ch = kk * 4 + (lane >> 4);
            int swz = ch ^ (row & 7);
            ahi = *(const bf16x8*)&sAh[row * 64 + swz * 8];
            alo = *(const bf16x8*)&sAl[row * 64 + swz * 8];
          }
#pragma unroll
          for (int fn = 0; fn < 2; ++fn) {
            int lr = wn * 32 + fn * 16 + (lane & 15);
            int ch = kk * 4 + (lane >> 4);
            int swz = ch ^ (lr & 7);
            bhi[fn] = *(const bf16x8*)&sBh[lr * 64 + swz * 8];
            blo[fn] = *(const bf16x8*)&sBl[lr * 64 + swz * 8];
          }
#pragma unroll
          for (int fn = 0; fn < 2; ++fn) {
            acc2[fn] = __builtin_amdgcn_mfma_f32_16x16x32_bf16(ahi, bhi[fn], acc2[fn], 0, 0, 0);
            acc2[fn] = __builtin_amdgcn_mfma_f32_16x16x32_bf16(ahi, blo[fn], acc2[fn], 0, 0, 0);
            acc2[fn] = __builtin_amdgcn_mfma_f32_16x16x32_bf16(alo, bhi[fn], acc2[fn], 0, 0, 0);
          }
        }
        __syncthreads();
      }

      // z -> LDS (zl overlays sBh; all reads done at loop-end barrier)
#pragma unroll
      for (int fn = 0; fn < 2; ++fn)
#pragma unroll
        for (int r = 0; r < 4; ++r) {
          int row = wm * 16 + (lane >> 4) * 4 + r;
          int col = wn * 32 + fn * 16 + (lane & 15);
          zl[row * 128 + col] = acc2[fn][r];
        }
      __syncthreads();

      // LSTM pointwise: 32 rows x 32 j = 1024 outputs, 512 thr x 2
#pragma unroll
      for (int i = 0; i < 2; ++i) {
        int p = tid + i * 512;
        int row = p >> 5, j = p & 31;
        int b = mBase + row, jc = j0 + j;
        int chr = a.text[b * NSTEP + s];
        const float* crow = a.lstm_kernel + (size_t)(512 + chr) * 2048;
        const float* hrec = a.qh + (size_t)b * 2560 + 512;
        float g4[4];
#pragma unroll
        for (int g = 0; g < 4; ++g) {
          int col = g * 512 + jc;
          g4[g] = zl[row * 128 + g * 32 + j] + hrec[col] + a.lstm_bias[col] + crow[col];
        }
        float iv = sigmoid_fast(g4[0]);
        float fv = sigmoid_fast(g4[1]);
        float gv = tanh_fast(g4[2]);
        float ov = sigmoid_fast(g4[3]);
        size_t gi = (size_t)b * 512 + jc;
        float c = fv * a.cstate[gi] + iv * gv;
        a.cstate[gi] = c;
        float hv = ov * tanh_fast(c);
        __hip_bfloat16 hh, hl;
        split2(hv, hh, hl);
        a.hsh[(size_t)(s + 1) * 262144 + gi] = hh;
        a.hsl[(size_t)(s + 1) * 262144 + gi] = hl;
      }
    }
    bar_target += NBLK;
    grid_sync(a.bar, bar_target);
  }
}

// ---------------------------------------------------------------------------
extern "C" void kernel_launch(void* const* d_in, const int* in_sizes, int n_in,
                              void* d_out, int out_size, void* d_ws, size_t ws_size,
                              hipStream_t stream) {
  (void)in_sizes; (void)n_in; (void)out_size; (void)ws_size;
  const float* batch_H = (const float*)d_in[0];
  const int* text = (const int*)d_in[1];
  const float* Wi = (const float*)d_in[3];
  const float* Wh = (const float*)d_in[4];
  const float* bh = (const float*)d_in[5];
  const float* Ws = (const float*)d_in[6];
  const float* lstm_kernel = (const float*)d_in[7];
  const float* lstm_rec = (const float*)d_in[8];
  const float* lstm_bias = (const float*)d_in[9];
  const float* Wgen = (const float*)d_in[10];
  const float* bgen = (const float*)d_in[11];
  float* out = (float*)d_out;

  char* w = (char*)d_ws;
  auto alloc = [&](size_t bytes) {
    char* p = w;
    w += (bytes + 255) & ~(size_t)255;
    return p;
  };
  const size_t NE = 32768ull * 512;
  __hip_bfloat16* bAh = (__hip_bfloat16*)alloc(NE * 2);
  char* bAl_region = alloc(NE * 2);   // dead after Hproj; reused for hs/ctx
  __hip_bfloat16* bAl = (__hip_bfloat16*)bAl_region;
  __hip_bfloat16* Hp16 = (__hip_bfloat16*)alloc(NE * 2);
  __hip_bfloat16* WiT_h = (__hip_bfloat16*)alloc(512ull * 512 * 2);
  __hip_bfloat16* WiT_l = (__hip_bfloat16*)alloc(512ull * 512 * 2);
  __hip_bfloat16* W2T_h = (__hip_bfloat16*)alloc(2560ull * 512 * 2);
  __hip_bfloat16* W2T_l = (__hip_bfloat16*)alloc(2560ull * 512 * 2);
  __hip_bfloat16* K1T_h = (__hip_bfloat16*)alloc(2048ull * 512 * 2);
  __hip_bfloat16* K1T_l = (__hip_bfloat16*)alloc(2048ull * 512 * 2);
  __hip_bfloat16* WgT_h = (__hip_bfloat16*)alloc(128ull * 512 * 2);
  __hip_bfloat16* WgT_l = (__hip_bfloat16*)alloc(128ull * 512 * 2);
  float* qh = (float*)alloc(512ull * 2560 * 4);
  float* cstate = (float*)alloc(512ull * 512 * 4);
  unsigned* bar = (unsigned*)alloc(256);
  __hip_bfloat16* hsh = (__hip_bfloat16*)bAl_region;
  __hip_bfloat16* hsl = (__hip_bfloat16*)(bAl_region + 27ull * 262144 * 2);
  __hip_bfloat16* ctxh = (__hip_bfloat16*)(bAl_region + 2ull * 27 * 262144 * 2);
  __hip_bfloat16* ctxl = ctxh + 512ull * 512;

  split_pair<<<dim3(8192), 256, 0, stream>>>(batch_H, bAh, bAl, (int)(NE / 8));
  dim3 tb(32, 8, 1);
  transpose_split<<<dim3(16, 16), tb, 0, stream>>>(Wi, 512, 512, Wi, 512, 512, WiT_h, WiT_l);
  transpose_split<<<dim3(80, 16), tb, 0, stream>>>(Wh, 512, 512, lstm_rec, 2048, 2560, W2T_h, W2T_l);
  transpose_split<<<dim3(64, 16), tb, 0, stream>>>(lstm_kernel, 2048, 2048, lstm_kernel, 2048, 2048, K1T_h, K1T_l);
  transpose_split<<<dim3(4, 16), tb, 0, stream>>>(Wgen, 96, 96, Wgen, 96, 96, WgT_h, WgT_l);

  gemm_pre<2><<<dim3(8, 256), 256, 0, stream>>>(bAh, bAl, WiT_h, WiT_l,
                                                nullptr, Hp16, nullptr);

  hipMemsetAsync(hsh, 0, 262144ull * 2, stream);
  hipMemsetAsync(hsl, 0, 262144ull * 2, stream);
  hipMemsetAsync(cstate, 0, 512ull * 512 * 4, stream);
  hipMemsetAsync(bar, 0, 256, stream);

  DecodeArgs args;
  args.W2h = W2T_h; args.W2l = W2T_l;
  args.K1h = K1T_h; args.K1l = K1T_l;
  args.Hp16 = Hp16; args.bAh = bAh;
  args.bh = bh; args.Ws = Ws; args.lstm_bias = lstm_bias; args.lstm_kernel = lstm_kernel;
  args.text = text;
  args.qh = qh; args.cstate = cstate;
  args.ctxh = ctxh; args.ctxl = ctxl; args.hsh = hsh; args.hsl = hsl;
  args.bar = bar;
  decode_loop<<<dim3(NBLK), 512, 0, stream>>>(args);

  gemm_pre<1><<<dim3(2, 104), 256, 0, stream>>>(hsh + 262144, hsl + 262144,
                                                WgT_h, WgT_l, out, nullptr, bgen);
}

// Round 8
// 2451.425 us; speedup vs baseline: 1.8258x; 1.6001x over previous
//
#include <hip/hip_runtime.h>
#include <hip/hip_bf16.h>

// B=512, T=64, C=512, H=512, NC=96, S=26.
// XCD-sharded persistent decoder:
//   - 256 blocks x 512 thr; shard = blockIdx%8 (32 blocks = 1 XCD under
//     round-robin dispatch), owns batch rows [shard*64, shard*64+64).
//   - Per step, per shard: {SP1 qh-GEMM | SP2 attn | SP3 z-GEMM+LSTM},
//     separated by PER-SHARD barriers (relaxed agent atomics + s_waitcnt
//     drain; NO acquire/release fences -> L2 never invalidated, weights
//     stay cache-resident across steps).
//   - Phase-crossing activations (qh, ctx, h ping-pong) via relaxed
//     agent-scope atomic scalar loads/stores (coherent, no fences).
//     Weights/Hproj/batch_H are read-only plain cacheable loads.
// All GEMMs: 3-pass bf16-split MFMA (~fp32 precision).

#define NSTEP 26
#define NBLK 256

typedef __bf16 bf16x8 __attribute__((ext_vector_type(8)));
typedef float f32x4 __attribute__((ext_vector_type(4)));

__device__ __forceinline__ float tanh_fast(float x) {
  float e = __expf(2.0f * x);
  return 1.0f - 2.0f / (e + 1.0f);
}
__device__ __forceinline__ float sigmoid_fast(float x) {
  return 1.0f / (1.0f + __expf(-x));
}
__device__ __forceinline__ float bflo(unsigned u) {
  union { unsigned i; float f; } c; c.i = u << 16; return c.f;
}
__device__ __forceinline__ float bfhi(unsigned u) {
  union { unsigned i; float f; } c; c.i = u & 0xffff0000u; return c.f;
}
__device__ __forceinline__ void split2(float v, __hip_bfloat16& h, __hip_bfloat16& l) {
  h = __float2bfloat16(v);
  l = __float2bfloat16(v - __bfloat162float(h));
}

__device__ __forceinline__ float cohL(const float* p) {
  return __hip_atomic_load(p, __ATOMIC_RELAXED, __HIP_MEMORY_SCOPE_AGENT);
}
__device__ __forceinline__ void cohS(float* p, float v) {
  __hip_atomic_store(p, v, __ATOMIC_RELAXED, __HIP_MEMORY_SCOPE_AGENT);
}

// Per-shard barrier (32 arrivals). Every wave drains its own vmem/lds
// counters first (stores committed), then thread 0 arrives; relaxed
// atomics only -> no L2 writeback/invalidate.
__device__ __forceinline__ void shard_sync(unsigned* cnt, unsigned target) {
  __builtin_amdgcn_s_waitcnt(0);
  __syncthreads();
  if (threadIdx.x == 0) {
    __hip_atomic_fetch_add(cnt, 1u, __ATOMIC_RELAXED, __HIP_MEMORY_SCOPE_AGENT);
    while (__hip_atomic_load(cnt, __ATOMIC_RELAXED, __HIP_MEMORY_SCOPE_AGENT) < target)
      __builtin_amdgcn_s_sleep(2);
  }
  __syncthreads();
}

// ---------------------------------------------------------------------------
__global__ __launch_bounds__(256) void split_pair(
    const float* __restrict__ src, __hip_bfloat16* __restrict__ hi,
    __hip_bfloat16* __restrict__ lo, int n8) {
  int idx = blockIdx.x * 256 + threadIdx.x;
  if (idx >= n8) return;
  const float* s = src + (size_t)idx * 8;
  float4 v0 = *(const float4*)s, v1 = *(const float4*)(s + 4);
  float vv[8] = {v0.x, v0.y, v0.z, v0.w, v1.x, v1.y, v1.z, v1.w};
  union { int4 q; __hip_bfloat16 h[8]; } uh, ul;
#pragma unroll
  for (int j = 0; j < 8; ++j) split2(vv[j], uh.h[j], ul.h[j]);
  *(int4*)&hi[(size_t)idx * 8] = uh.q;
  *(int4*)&lo[(size_t)idx * 8] = ul.q;
}

// ---------------------------------------------------------------------------
__global__ __launch_bounds__(256) void transpose_split(
    const float* __restrict__ srcA, int ldA, int NA,
    const float* __restrict__ srcB, int ldB, int Nvalid,
    __hip_bfloat16* __restrict__ hi, __hip_bfloat16* __restrict__ lo) {
  __shared__ float tile[32][33];
  const int tx = threadIdx.x, ty = threadIdx.y;
  const int n0 = blockIdx.x * 32, k0 = blockIdx.y * 32;
#pragma unroll
  for (int i = 0; i < 4; ++i) {
    int k = k0 + ty + i * 8;
    int n = n0 + tx;
    float v = 0.f;
    if (n < NA) v = srcA[(size_t)k * ldA + n];
    else if (n < Nvalid) v = srcB[(size_t)k * ldB + (n - NA)];
    tile[tx][ty + i * 8] = v;
  }
  __syncthreads();
#pragma unroll
  for (int i = 0; i < 4; ++i) {
    int n = n0 + ty + i * 8;
    int k = k0 + tx;
    float v = tile[ty + i * 8][tx];
    __hip_bfloat16 h, l;
    split2(v, h, l);
    hi[(size_t)n * 512 + k] = h;
    lo[(size_t)n * 512 + k] = l;
  }
}

// ---------------------------------------------------------------------------
// 128x64 tile helper for the 256-thread pre/post GEMMs (unchanged).
// ---------------------------------------------------------------------------
__device__ __forceinline__ void tile128x64(
    const __hip_bfloat16* __restrict__ Ah, const __hip_bfloat16* __restrict__ Al,
    const __hip_bfloat16* __restrict__ Bh, const __hip_bfloat16* __restrict__ Bl,
    char* smem, int tid, f32x4 (&acc)[4][2]) {
  __hip_bfloat16* sAh = (__hip_bfloat16*)smem;
  __hip_bfloat16* sAl = sAh + 128 * 64;
  __hip_bfloat16* sBh = sAl + 128 * 64;
  __hip_bfloat16* sBl = sBh + 64 * 64;
  const int lane = tid & 63, wid = tid >> 6;
  const int mh = wid >> 1, nh = wid & 1;

  for (int kt = 0; kt < 8; ++kt) {
#pragma unroll
    for (int i = 0; i < 4; ++i) {
      int cid = tid + i * 256;
      int row = cid >> 3, ch = cid & 7;
      int swz = ch ^ (row & 7);
      size_t g = (size_t)row * 512 + kt * 64 + ch * 8;
      *(int4*)&sAh[row * 64 + swz * 8] = *(const int4*)&Ah[g];
      *(int4*)&sAl[row * 64 + swz * 8] = *(const int4*)&Al[g];
    }
#pragma unroll
    for (int i = 0; i < 2; ++i) {
      int cid = tid + i * 256;
      int row = cid >> 3, ch = cid & 7;
      int swz = ch ^ (row & 7);
      size_t g = (size_t)row * 512 + kt * 64 + ch * 8;
      *(int4*)&sBh[row * 64 + swz * 8] = *(const int4*)&Bh[g];
      *(int4*)&sBl[row * 64 + swz * 8] = *(const int4*)&Bl[g];
    }
    __syncthreads();

#pragma unroll
    for (int kk = 0; kk < 2; ++kk) {
      bf16x8 ahi[4], alo[4], bhi[2], blo[2];
#pragma unroll
      for (int fm = 0; fm < 4; ++fm) {
        int row = mh * 64 + fm * 16 + (lane & 15);
        int ch = kk * 4 + (lane >> 4);
        int swz = ch ^ (row & 7);
        ahi[fm] = *(const bf16x8*)&sAh[row * 64 + swz * 8];
        alo[fm] = *(const bf16x8*)&sAl[row * 64 + swz * 8];
      }
#pragma unroll
      for (int fn = 0; fn < 2; ++fn) {
        int row = nh * 32 + fn * 16 + (lane & 15);
        int ch = kk * 4 + (lane >> 4);
        int swz = ch ^ (row & 7);
        bhi[fn] = *(const bf16x8*)&sBh[row * 64 + swz * 8];
        blo[fn] = *(const bf16x8*)&sBl[row * 64 + swz * 8];
      }
#pragma unroll
      for (int fm = 0; fm < 4; ++fm)
#pragma unroll
        for (int fn = 0; fn < 2; ++fn) {
          acc[fm][fn] = __builtin_amdgcn_mfma_f32_16x16x32_bf16(ahi[fm], bhi[fn], acc[fm][fn], 0, 0, 0);
          acc[fm][fn] = __builtin_amdgcn_mfma_f32_16x16x32_bf16(ahi[fm], blo[fn], acc[fm][fn], 0, 0, 0);
          acc[fm][fn] = __builtin_amdgcn_mfma_f32_16x16x32_bf16(alo[fm], bhi[fn], acc[fm][fn], 0, 0, 0);
        }
    }
    __syncthreads();
  }
}

// ---------------------------------------------------------------------------
template <int MODE>
__global__ __launch_bounds__(256) void gemm_pre(
    const __hip_bfloat16* __restrict__ Ah, const __hip_bfloat16* __restrict__ Al,
    const __hip_bfloat16* __restrict__ Bh, const __hip_bfloat16* __restrict__ Bl,
    float* __restrict__ outF, __hip_bfloat16* __restrict__ out16,
    const float* __restrict__ bias) {
  __shared__ __align__(16) char smem[49152];
  const int tid = threadIdx.x;
  const int lane = tid & 63, wid = tid >> 6;
  const int mh = wid >> 1, nh = wid & 1;

  int bx = blockIdx.x, by = blockIdx.y;
  if (MODE == 2) {
    int lid = by * 8 + bx;
    int xcd = lid & 7, k = lid >> 3;
    by = xcd * 32 + (k >> 3);
    bx = k & 7;
  }
  const int mBase = by * 128, nBase = bx * 64;

  f32x4 acc[4][2];
#pragma unroll
  for (int fm = 0; fm < 4; ++fm)
#pragma unroll
    for (int fn = 0; fn < 2; ++fn) acc[fm][fn] = (f32x4){0.f, 0.f, 0.f, 0.f};

  tile128x64(Ah + (size_t)mBase * 512, Al + (size_t)mBase * 512,
             Bh + (size_t)nBase * 512, Bl + (size_t)nBase * 512, smem, tid, acc);

#pragma unroll
  for (int fm = 0; fm < 4; ++fm)
#pragma unroll
    for (int fn = 0; fn < 2; ++fn)
#pragma unroll
      for (int r = 0; r < 4; ++r) {
        int row = mBase + mh * 64 + fm * 16 + (lane >> 4) * 4 + r;
        int col = nBase + nh * 32 + fn * 16 + (lane & 15);
        float v = acc[fm][fn][r];
        if (MODE == 2) {
          out16[(size_t)row * 512 + col] = __float2bfloat16(v);
        } else {
          int bb = row & 511, ss = row >> 9;   // A row = s*512 + b
          if (col < 96)
            outF[((size_t)bb * NSTEP + ss) * 96 + col] = v + bias[col];
        }
      }
}

// ---------------------------------------------------------------------------
// XCD-sharded persistent decode loop. 256 blocks x 512 threads.
// ---------------------------------------------------------------------------
struct DecodeArgs {
  const __hip_bfloat16 *W2h, *W2l;   // [2560][512]
  const __hip_bfloat16 *K1h, *K1l;   // [2048][512]
  const __hip_bfloat16 *Hp16, *bAh;  // [B*T][512]
  const float *bh, *Ws, *lstm_bias, *lstm_kernel;
  const int* text;
  float *qh, *cstate;
  float *hbuf;                        // [2][512*512] fp32 ping-pong
  float *ctxf;                        // [512*512] fp32
  __hip_bfloat16 *hsh, *hsl;          // [27][512*512] pairs (for probs)
  unsigned* bar;                      // 8 shard counters, 32-uint stride
};

__global__ __launch_bounds__(512) void decode_loop(DecodeArgs a) {
  __shared__ __align__(16) char smem[49152];
  const int tid = threadIdx.x;
  const int lane = tid & 63, wid = tid >> 6;
  const int shard = blockIdx.x & 7;     // = XCD under round-robin dispatch
  const int rank = blockIdx.x >> 3;     // 0..31 within shard
  const int rbase = shard * 64;         // batch rows owned by this shard
  unsigned* bar = a.bar + shard * 32;   // 128 B apart
  unsigned target = 0;
  const int wm = wid >> 1, wn = wid & 1;  // 4x2 wave grid, 64x64 tiles

  for (int s = 0; s < NSTEP; ++s) {
    const float* hcur = a.hbuf + (size_t)(s & 1) * 262144;
    float* hnxt = a.hbuf + (size_t)((s & 1) ^ 1) * 262144;

    // ---- SP1: qh[rbase..+63][2560] = h @ [Wh|lstm_rec]. 40 col-tiles of 64.
    {
      __hip_bfloat16* sAh = (__hip_bfloat16*)smem;   // 8 KB
      __hip_bfloat16* sAl = sAh + 64 * 64;           // 8 KB
      __hip_bfloat16* sBh = sAl + 64 * 64;           // 8 KB
      __hip_bfloat16* sBl = sBh + 64 * 64;           // 8 KB
      for (int ct = rank; ct < 40; ct += 32) {
        f32x4 acc[2];
        acc[0] = (f32x4){0.f, 0.f, 0.f, 0.f};
        acc[1] = (f32x4){0.f, 0.f, 0.f, 0.f};
        for (int kt = 0; kt < 8; ++kt) {
          {  // A stage: 64 rows x 64 k, fp32 coherent loads -> split
            int row = tid >> 3, ch = tid & 7;
            const float* src = hcur + (size_t)(rbase + row) * 512 + kt * 64 + ch * 8;
            union { int4 q; __hip_bfloat16 h[8]; } uh, ul;
#pragma unroll
            for (int j = 0; j < 8; ++j) split2(cohL(src + j), uh.h[j], ul.h[j]);
            int swz = ch ^ (row & 7);
            *(int4*)&sAh[row * 64 + swz * 8] = uh.q;
            *(int4*)&sAl[row * 64 + swz * 8] = ul.q;
          }
          {  // B stage: 64 col-rows x 64 k (plain, cacheable)
            int lr = tid >> 3, ch = tid & 7;
            int swz = ch ^ (lr & 7);
            size_t g = (size_t)(ct * 64 + lr) * 512 + kt * 64 + ch * 8;
            *(int4*)&sBh[lr * 64 + swz * 8] = *(const int4*)&a.W2h[g];
            *(int4*)&sBl[lr * 64 + swz * 8] = *(const int4*)&a.W2l[g];
          }
          __syncthreads();
#pragma unroll
          for (int kk = 0; kk < 2; ++kk) {
            bf16x8 ahi, alo, bhi[2], blo[2];
            {
              int row = wm * 16 + (lane & 15);
              int ch = kk * 4 + (lane >> 4);
              int swz = ch ^ (row & 7);
              ahi = *(const bf16x8*)&sAh[row * 64 + swz * 8];
              alo = *(const bf16x8*)&sAl[row * 64 + swz * 8];
            }
#pragma unroll
            for (int fn = 0; fn < 2; ++fn) {
              int lr = wn * 32 + fn * 16 + (lane & 15);
              int ch = kk * 4 + (lane >> 4);
              int swz = ch ^ (lr & 7);
              bhi[fn] = *(const bf16x8*)&sBh[lr * 64 + swz * 8];
              blo[fn] = *(const bf16x8*)&sBl[lr * 64 + swz * 8];
            }
#pragma unroll
            for (int fn = 0; fn < 2; ++fn) {
              acc[fn] = __builtin_amdgcn_mfma_f32_16x16x32_bf16(ahi, bhi[fn], acc[fn], 0, 0, 0);
              acc[fn] = __builtin_amdgcn_mfma_f32_16x16x32_bf16(ahi, blo[fn], acc[fn], 0, 0, 0);
              acc[fn] = __builtin_amdgcn_mfma_f32_16x16x32_bf16(alo, bhi[fn], acc[fn], 0, 0, 0);
            }
          }
          __syncthreads();
        }
#pragma unroll
        for (int fn = 0; fn < 2; ++fn)
#pragma unroll
          for (int r = 0; r < 4; ++r) {
            int row = wm * 16 + (lane >> 4) * 4 + r;
            int col = ct * 64 + wn * 32 + fn * 16 + (lane & 15);
            cohS(&a.qh[(size_t)(rbase + row) * 2560 + col], acc[fn][r]);
          }
      }
    }
    target += 32;
    shard_sync(bar, target);

    // ---- SP2: attention, rows rbase + rank*2 + {0,1} in parallel halves.
    {
      const int half = tid >> 8, ltid = tid & 255, w4 = wid & 3;
      const int b = rbase + rank * 2 + half;
      float* es = (float*)smem;     // [2][64]
      float* als = es + 128;        // [2][64]

      float qv[8], wv[8];
      {
        const float* qp = a.qh + (size_t)b * 2560 + lane * 8;
        const float* bp = a.bh + lane * 8;
        const float* wp = a.Ws + lane * 8;
        float4 h0 = *(const float4*)bp, h1 = *(const float4*)(bp + 4);
        float4 w0 = *(const float4*)wp, w1 = *(const float4*)(wp + 4);
        qv[0] = cohL(qp + 0) + h0.x; qv[1] = cohL(qp + 1) + h0.y;
        qv[2] = cohL(qp + 2) + h0.z; qv[3] = cohL(qp + 3) + h0.w;
        qv[4] = cohL(qp + 4) + h1.x; qv[5] = cohL(qp + 5) + h1.y;
        qv[6] = cohL(qp + 6) + h1.z; qv[7] = cohL(qp + 7) + h1.w;
        wv[0] = w0.x; wv[1] = w0.y; wv[2] = w0.z; wv[3] = w0.w;
        wv[4] = w1.x; wv[5] = w1.y; wv[6] = w1.z; wv[7] = w1.w;
      }
      const __hip_bfloat16* Hp = a.Hp16 + (size_t)b * 32768;
#pragma unroll
      for (int i = 0; i < 16; ++i) {
        int t = w4 * 16 + i;
        uint4 p = *(const uint4*)(Hp + (size_t)t * 512 + lane * 8);
        float sum = wv[0] * tanh_fast(bflo(p.x) + qv[0]) + wv[1] * tanh_fast(bfhi(p.x) + qv[1]) +
                    wv[2] * tanh_fast(bflo(p.y) + qv[2]) + wv[3] * tanh_fast(bfhi(p.y) + qv[3]) +
                    wv[4] * tanh_fast(bflo(p.z) + qv[4]) + wv[5] * tanh_fast(bfhi(p.z) + qv[5]) +
                    wv[6] * tanh_fast(bflo(p.w) + qv[6]) + wv[7] * tanh_fast(bfhi(p.w) + qv[7]);
#pragma unroll
        for (int off = 32; off; off >>= 1) sum += __shfl_xor(sum, off);
        if (lane == 0) es[half * 64 + t] = sum;
      }
      __syncthreads();
      if (w4 == 0) {
        float e = es[half * 64 + lane];
        float m = e;
#pragma unroll
        for (int off = 32; off; off >>= 1) m = fmaxf(m, __shfl_xor(m, off));
        float p = __expf(e - m);
        float sm = p;
#pragma unroll
        for (int off = 32; off; off >>= 1) sm += __shfl_xor(sm, off);
        als[half * 64 + lane] = p / sm;
      }
      __syncthreads();
      const unsigned* Bp = (const unsigned*)(a.bAh + (size_t)b * 32768);
      float sx = 0.f, sy = 0.f;
#pragma unroll 8
      for (int t = 0; t < 64; ++t) {
        unsigned u = Bp[t * 256 + ltid];
        float al = als[half * 64 + t];
        sx += al * bflo(u);
        sy += al * bfhi(u);
      }
      cohS(&a.ctxf[(size_t)b * 512 + ltid * 2 + 0], sx);
      cohS(&a.ctxf[(size_t)b * 512 + ltid * 2 + 1], sy);
    }
    target += 32;
    shard_sync(bar, target);

    // ---- SP3: z[64 x 64 gate-strided cols] = ctx @ K1, + fused LSTM.
    // rank -> j-chunk of 16 (x4 gates). All 32 blocks busy.
    {
      const int j0 = rank * 16;
      __hip_bfloat16* sAh = (__hip_bfloat16*)smem;   // 8 KB
      __hip_bfloat16* sAl = sAh + 64 * 64;           // 8 KB
      __hip_bfloat16* sBh = sAl + 64 * 64;           // 8 KB
      __hip_bfloat16* sBl = sBh + 64 * 64;           // 8 KB
      float* zl = (float*)(smem + 32768);            // 16 KB [64][64]

      f32x4 acc[2];
      acc[0] = (f32x4){0.f, 0.f, 0.f, 0.f};
      acc[1] = (f32x4){0.f, 0.f, 0.f, 0.f};
      for (int kt = 0; kt < 8; ++kt) {
        {  // A stage: ctx 64 rows x 64 k fp32 coherent -> split
          int row = tid >> 3, ch = tid & 7;
          const float* src = a.ctxf + (size_t)(rbase + row) * 512 + kt * 64 + ch * 8;
          union { int4 q; __hip_bfloat16 h[8]; } uh, ul;
#pragma unroll
          for (int j = 0; j < 8; ++j) split2(cohL(src + j), uh.h[j], ul.h[j]);
          int swz = ch ^ (row & 7);
          *(int4*)&sAh[row * 64 + swz * 8] = uh.q;
          *(int4*)&sAl[row * 64 + swz * 8] = ul.q;
        }
        {  // B stage: 64 local rows = gate(4) x jj(16), plain cacheable
          int lr = tid >> 3, ch = tid & 7;
          int gate = lr >> 4, jj = lr & 15;
          int swz = ch ^ (lr & 7);
          size_t g = (size_t)(gate * 512 + j0 + jj) * 512 + kt * 64 + ch * 8;
          *(int4*)&sBh[lr * 64 + swz * 8] = *(const int4*)&a.K1h[g];
          *(int4*)&sBl[lr * 64 + swz * 8] = *(const int4*)&a.K1l[g];
        }
        __syncthreads();
#pragma unroll
        for (int kk = 0; kk < 2; ++kk) {
          bf16x8 ahi, alo, bhi[2], blo[2];
          {
            int row = wm * 16 + (lane & 15);
            int ch = kk * 4 + (lane >> 4);
            int swz = ch ^ (row & 7);
            ahi = *(const bf16x8*)&sAh[row * 64 + swz * 8];
            alo = *(const bf16x8*)&sAl[row * 64 + swz * 8];
          }
#pragma unroll
          for (int fn = 0; fn < 2; ++fn) {
            int lr = wn * 32 + fn * 16 + (lane & 15);
            int ch = kk * 4 + (lane >> 4);
            int swz = ch ^ (lr & 7);
            bhi[fn] = *(const bf16x8*)&sBh[lr * 64 + swz * 8];
            blo[fn] = *(const bf16x8*)&sBl[lr * 64 + swz * 8];
          }
#pragma unroll
          for (int fn = 0; fn < 2; ++fn) {
            acc[fn] = __builtin_amdgcn_mfma_f32_16x16x32_bf16(ahi, bhi[fn], acc[fn], 0, 0, 0);
            acc[fn] = __builtin_amdgcn_mfma_f32_16x16x32_bf16(ahi, blo[fn], acc[fn], 0, 0, 0);
            acc[fn] = __builtin_amdgcn_mfma_f32_16x16x32_bf16(alo, bhi[fn], acc[fn], 0, 0, 0);
          }
        }
        __syncthreads();
      }
      // z -> LDS
#pragma unroll
      for (int fn = 0; fn < 2; ++fn)
#pragma unroll
        for (int r = 0; r < 4; ++r) {
          int row = wm * 16 + (lane >> 4) * 4 + r;
          int col = wn * 32 + fn * 16 + (lane & 15);
          zl[row * 64 + col] = acc[fn][r];
        }
      __syncthreads();

      // LSTM pointwise: 64 rows x 16 j = 1024 outputs
#pragma unroll
      for (int i = 0; i < 2; ++i) {
        int p = tid + i * 512;
        int row = p >> 4, j = p & 15;
        int b = rbase + row, jc = j0 + j;
        int chr = a.text[b * NSTEP + s];
        const float* crow = a.lstm_kernel + (size_t)(512 + chr) * 2048;
        float g4[4];
#pragma unroll
        for (int g = 0; g < 4; ++g) {
          int col = g * 512 + jc;
          g4[g] = zl[row * 64 + g * 16 + j] +
                  cohL(&a.qh[(size_t)b * 2560 + 512 + col]) +
                  a.lstm_bias[col] + crow[col];
        }
        float iv = sigmoid_fast(g4[0]);
        float fv = sigmoid_fast(g4[1]);
        float gv = tanh_fast(g4[2]);
        float ov = sigmoid_fast(g4[3]);
        size_t gi = (size_t)b * 512 + jc;
        float c = fv * a.cstate[gi] + iv * gv;   // same block each step: plain
        a.cstate[gi] = c;
        float hv = ov * tanh_fast(c);
        cohS(&hnxt[gi], hv);
        __hip_bfloat16 hh, hl;
        split2(hv, hh, hl);
        a.hsh[(size_t)(s + 1) * 262144 + gi] = hh;  // plain: read post-kernel
        a.hsl[(size_t)(s + 1) * 262144 + gi] = hl;
      }
    }
    target += 32;
    shard_sync(bar, target);
  }
}

// ---------------------------------------------------------------------------
extern "C" void kernel_launch(void* const* d_in, const int* in_sizes, int n_in,
                              void* d_out, int out_size, void* d_ws, size_t ws_size,
                              hipStream_t stream) {
  (void)in_sizes; (void)n_in; (void)out_size; (void)ws_size;
  const float* batch_H = (const float*)d_in[0];
  const int* text = (const int*)d_in[1];
  const float* Wi = (const float*)d_in[3];
  const float* Wh = (const float*)d_in[4];
  const float* bh = (const float*)d_in[5];
  const float* Ws = (const float*)d_in[6];
  const float* lstm_kernel = (const float*)d_in[7];
  const float* lstm_rec = (const float*)d_in[8];
  const float* lstm_bias = (const float*)d_in[9];
  const float* Wgen = (const float*)d_in[10];
  const float* bgen = (const float*)d_in[11];
  float* out = (float*)d_out;

  char* w = (char*)d_ws;
  auto alloc = [&](size_t bytes) {
    char* p = w;
    w += (bytes + 255) & ~(size_t)255;
    return p;
  };
  const size_t NE = 32768ull * 512;
  __hip_bfloat16* bAh = (__hip_bfloat16*)alloc(NE * 2);
  char* bAl_region = alloc(NE * 2);   // dead after Hproj; reused below
  __hip_bfloat16* bAl = (__hip_bfloat16*)bAl_region;
  __hip_bfloat16* Hp16 = (__hip_bfloat16*)alloc(NE * 2);
  __hip_bfloat16* WiT_h = (__hip_bfloat16*)alloc(512ull * 512 * 2);
  __hip_bfloat16* WiT_l = (__hip_bfloat16*)alloc(512ull * 512 * 2);
  __hip_bfloat16* W2T_h = (__hip_bfloat16*)alloc(2560ull * 512 * 2);
  __hip_bfloat16* W2T_l = (__hip_bfloat16*)alloc(2560ull * 512 * 2);
  __hip_bfloat16* K1T_h = (__hip_bfloat16*)alloc(2048ull * 512 * 2);
  __hip_bfloat16* K1T_l = (__hip_bfloat16*)alloc(2048ull * 512 * 2);
  __hip_bfloat16* WgT_h = (__hip_bfloat16*)alloc(128ull * 512 * 2);
  __hip_bfloat16* WgT_l = (__hip_bfloat16*)alloc(128ull * 512 * 2);
  float* qh = (float*)alloc(512ull * 2560 * 4);
  float* cstate = (float*)alloc(512ull * 512 * 4);
  unsigned* bar = (unsigned*)alloc(1024);   // 8 shards x 32 uints
  // Aliases inside the dead bAl region:
  __hip_bfloat16* hsh = (__hip_bfloat16*)bAl_region;                         // 14.16 MB
  __hip_bfloat16* hsl = (__hip_bfloat16*)(bAl_region + 27ull * 262144 * 2);  // 14.16 MB
  float* hbuf = (float*)(bAl_region + 2ull * 27 * 262144 * 2);               // 2 MB
  float* ctxf = (float*)(bAl_region + 2ull * 27 * 262144 * 2 + 2097152);     // 1 MB

  split_pair<<<dim3(8192), 256, 0, stream>>>(batch_H, bAh, bAl, (int)(NE / 8));
  dim3 tb(32, 8, 1);
  transpose_split<<<dim3(16, 16), tb, 0, stream>>>(Wi, 512, 512, Wi, 512, 512, WiT_h, WiT_l);
  transpose_split<<<dim3(80, 16), tb, 0, stream>>>(Wh, 512, 512, lstm_rec, 2048, 2560, W2T_h, W2T_l);
  transpose_split<<<dim3(64, 16), tb, 0, stream>>>(lstm_kernel, 2048, 2048, lstm_kernel, 2048, 2048, K1T_h, K1T_l);
  transpose_split<<<dim3(4, 16), tb, 0, stream>>>(Wgen, 96, 96, Wgen, 96, 96, WgT_h, WgT_l);

  gemm_pre<2><<<dim3(8, 256), 256, 0, stream>>>(bAh, bAl, WiT_h, WiT_l,
                                                nullptr, Hp16, nullptr);

  hipMemsetAsync(hbuf, 0, 262144ull * 4, stream);      // h_{-1} = 0 (slot 0)
  hipMemsetAsync(cstate, 0, 512ull * 512 * 4, stream);
  hipMemsetAsync(bar, 0, 1024, stream);

  DecodeArgs args;
  args.W2h = W2T_h; args.W2l = W2T_l;
  args.K1h = K1T_h; args.K1l = K1T_l;
  args.Hp16 = Hp16; args.bAh = bAh;
  args.bh = bh; args.Ws = Ws; args.lstm_bias = lstm_bias; args.lstm_kernel = lstm_kernel;
  args.text = text;
  args.qh = qh; args.cstate = cstate;
  args.hbuf = hbuf; args.ctxf = ctxf;
  args.hsh = hsh; args.hsl = hsl;
  args.bar = bar;
  decode_loop<<<dim3(NBLK), 512, 0, stream>>>(args);

  gemm_pre<1><<<dim3(2, 104), 256, 0, stream>>>(hsh + 262144, hsl + 262144,
                                                WgT_h, WgT_l, out, nullptr, bgen);
}

// Round 9
// 1781.213 us; speedup vs baseline: 2.5128x; 1.3763x over previous
//
#include <hip/hip_runtime.h>
#include <hip/hip_bf16.h>

// B=512, T=64, C=512, H=512, NC=96, S=26.
// XCD-sharded persistent decoder (R9):
//   - 256 blocks x 512 thr; shard = blockIdx%8 (32 blocks), owns rows
//     [shard*64, shard*64+64) for all 26 steps.
//   - Per step: {SP1: q = h@Wh (8 blocks, 64x64 tile each) |
//                SP2: attention (32 blocks x 2 rows)       |
//                SP3: z = [ctx|h] @ [K1|W2rec] K=1024 concat GEMM
//                     + fused LSTM pointwise (32 blocks x 64-col slice)}
//   - Barriers: per-shard FLAG-ARRAY barrier (store own flag, wave0 polls
//     all 32 via one lane-parallel relaxed load + __all). No RMW -> no
//     L3 atomic serialization. s_waitcnt(0) before arrival publishes data.
//   - Cross-phase activations: 8-byte relaxed agent-scope atomics
//     (coherent at L3, no fences -> L2 weight residency preserved).
// All GEMMs: 3-pass bf16-split MFMA (Ahi*Bhi + Ahi*Blo + Alo*Bhi ~ fp32).

#define NSTEP 26
#define NBLK 256

typedef __bf16 bf16x8 __attribute__((ext_vector_type(8)));
typedef float f32x4 __attribute__((ext_vector_type(4)));

__device__ __forceinline__ float tanh_fast(float x) {
  float e = __expf(2.0f * x);
  return 1.0f - 2.0f / (e + 1.0f);
}
__device__ __forceinline__ float sigmoid_fast(float x) {
  return 1.0f / (1.0f + __expf(-x));
}
__device__ __forceinline__ float bflo(unsigned u) {
  union { unsigned i; float f; } c; c.i = u << 16; return c.f;
}
__device__ __forceinline__ float bfhi(unsigned u) {
  union { unsigned i; float f; } c; c.i = u & 0xffff0000u; return c.f;
}
__device__ __forceinline__ void split2(float v, __hip_bfloat16& h, __hip_bfloat16& l) {
  h = __float2bfloat16(v);
  l = __float2bfloat16(v - __bfloat162float(h));
}

// 8-byte relaxed agent-scope transport (coherent at L3, no fences).
__device__ __forceinline__ float2 cohL2(const float* p) {
  unsigned long long v = __hip_atomic_load((const unsigned long long*)p,
                                           __ATOMIC_RELAXED, __HIP_MEMORY_SCOPE_AGENT);
  union { unsigned long long u; float2 f; } c; c.u = v; return c.f;
}
__device__ __forceinline__ void cohS2(float* p, float a, float b) {
  union { unsigned long long u; float2 f; } c; c.f = make_float2(a, b);
  __hip_atomic_store((unsigned long long*)p, c.u,
                     __ATOMIC_RELAXED, __HIP_MEMORY_SCOPE_AGENT);
}
__device__ __forceinline__ void cohS(float* p, float v) {
  __hip_atomic_store(p, v, __ATOMIC_RELAXED, __HIP_MEMORY_SCOPE_AGENT);
}

// Flag-array shard barrier: store own epoch flag (no RMW), wave0 polls all
// 32 flags with one relaxed load per lane. s_waitcnt(0)+syncthreads first
// ensures every wave's stores reached L3 before the flag is published.
__device__ __forceinline__ void shard_sync(unsigned* flags, int rank,
                                           unsigned tgt, int tid) {
  __builtin_amdgcn_s_waitcnt(0);
  __syncthreads();
  if (tid == 0)
    __hip_atomic_store(&flags[rank], tgt, __ATOMIC_RELAXED, __HIP_MEMORY_SCOPE_AGENT);
  if (tid < 64) {
    for (;;) {
      unsigned v = (tid < 32)
        ? __hip_atomic_load(&flags[tid], __ATOMIC_RELAXED, __HIP_MEMORY_SCOPE_AGENT)
        : tgt;
      if (__all(v >= tgt)) break;
      __builtin_amdgcn_s_sleep(1);
    }
  }
  __syncthreads();
}

// ---------------------------------------------------------------------------
__global__ __launch_bounds__(256) void split_pair(
    const float* __restrict__ src, __hip_bfloat16* __restrict__ hi,
    __hip_bfloat16* __restrict__ lo, int n8) {
  int idx = blockIdx.x * 256 + threadIdx.x;
  if (idx >= n8) return;
  const float* s = src + (size_t)idx * 8;
  float4 v0 = *(const float4*)s, v1 = *(const float4*)(s + 4);
  float vv[8] = {v0.x, v0.y, v0.z, v0.w, v1.x, v1.y, v1.z, v1.w};
  union { int4 q; __hip_bfloat16 h[8]; } uh, ul;
#pragma unroll
  for (int j = 0; j < 8; ++j) split2(vv[j], uh.h[j], ul.h[j]);
  *(int4*)&hi[(size_t)idx * 8] = uh.q;
  *(int4*)&lo[(size_t)idx * 8] = ul.q;
}

// ---------------------------------------------------------------------------
__global__ __launch_bounds__(256) void transpose_split(
    const float* __restrict__ srcA, int ldA, int NA,
    const float* __restrict__ srcB, int ldB, int Nvalid,
    __hip_bfloat16* __restrict__ hi, __hip_bfloat16* __restrict__ lo) {
  __shared__ float tile[32][33];
  const int tx = threadIdx.x, ty = threadIdx.y;
  const int n0 = blockIdx.x * 32, k0 = blockIdx.y * 32;
#pragma unroll
  for (int i = 0; i < 4; ++i) {
    int k = k0 + ty + i * 8;
    int n = n0 + tx;
    float v = 0.f;
    if (n < NA) v = srcA[(size_t)k * ldA + n];
    else if (n < Nvalid) v = srcB[(size_t)k * ldB + (n - NA)];
    tile[tx][ty + i * 8] = v;
  }
  __syncthreads();
#pragma unroll
  for (int i = 0; i < 4; ++i) {
    int n = n0 + ty + i * 8;
    int k = k0 + tx;
    float v = tile[ty + i * 8][tx];
    __hip_bfloat16 h, l;
    split2(v, h, l);
    hi[(size_t)n * 512 + k] = h;
    lo[(size_t)n * 512 + k] = l;
  }
}

// ---------------------------------------------------------------------------
// 128x64 tile helper for the 256-thread pre/post GEMMs (unchanged).
// ---------------------------------------------------------------------------
__device__ __forceinline__ void tile128x64(
    const __hip_bfloat16* __restrict__ Ah, const __hip_bfloat16* __restrict__ Al,
    const __hip_bfloat16* __restrict__ Bh, const __hip_bfloat16* __restrict__ Bl,
    char* smem, int tid, f32x4 (&acc)[4][2]) {
  __hip_bfloat16* sAh = (__hip_bfloat16*)smem;
  __hip_bfloat16* sAl = sAh + 128 * 64;
  __hip_bfloat16* sBh = sAl + 128 * 64;
  __hip_bfloat16* sBl = sBh + 64 * 64;
  const int lane = tid & 63, wid = tid >> 6;
  const int mh = wid >> 1, nh = wid & 1;

  for (int kt = 0; kt < 8; ++kt) {
#pragma unroll
    for (int i = 0; i < 4; ++i) {
      int cid = tid + i * 256;
      int row = cid >> 3, ch = cid & 7;
      int swz = ch ^ (row & 7);
      size_t g = (size_t)row * 512 + kt * 64 + ch * 8;
      *(int4*)&sAh[row * 64 + swz * 8] = *(const int4*)&Ah[g];
      *(int4*)&sAl[row * 64 + swz * 8] = *(const int4*)&Al[g];
    }
#pragma unroll
    for (int i = 0; i < 2; ++i) {
      int cid = tid + i * 256;
      int row = cid >> 3, ch = cid & 7;
      int swz = ch ^ (row & 7);
      size_t g = (size_t)row * 512 + kt * 64 + ch * 8;
      *(int4*)&sBh[row * 64 + swz * 8] = *(const int4*)&Bh[g];
      *(int4*)&sBl[row * 64 + swz * 8] = *(const int4*)&Bl[g];
    }
    __syncthreads();

#pragma unroll
    for (int kk = 0; kk < 2; ++kk) {
      bf16x8 ahi[4], alo[4], bhi[2], blo[2];
#pragma unroll
      for (int fm = 0; fm < 4; ++fm) {
        int row = mh * 64 + fm * 16 + (lane & 15);
        int ch = kk * 4 + (lane >> 4);
        int swz = ch ^ (row & 7);
        ahi[fm] = *(const bf16x8*)&sAh[row * 64 + swz * 8];
        alo[fm] = *(const bf16x8*)&sAl[row * 64 + swz * 8];
      }
#pragma unroll
      for (int fn = 0; fn < 2; ++fn) {
        int row = nh * 32 + fn * 16 + (lane & 15);
        int ch = kk * 4 + (lane >> 4);
        int swz = ch ^ (row & 7);
        bhi[fn] = *(const bf16x8*)&sBh[row * 64 + swz * 8];
        blo[fn] = *(const bf16x8*)&sBl[row * 64 + swz * 8];
      }
#pragma unroll
      for (int fm = 0; fm < 4; ++fm)
#pragma unroll
        for (int fn = 0; fn < 2; ++fn) {
          acc[fm][fn] = __builtin_amdgcn_mfma_f32_16x16x32_bf16(ahi[fm], bhi[fn], acc[fm][fn], 0, 0, 0);
          acc[fm][fn] = __builtin_amdgcn_mfma_f32_16x16x32_bf16(ahi[fm], blo[fn], acc[fm][fn], 0, 0, 0);
          acc[fm][fn] = __builtin_amdgcn_mfma_f32_16x16x32_bf16(alo[fm], bhi[fn], acc[fm][fn], 0, 0, 0);
        }
    }
    __syncthreads();
  }
}

// ---------------------------------------------------------------------------
template <int MODE>
__global__ __launch_bounds__(256) void gemm_pre(
    const __hip_bfloat16* __restrict__ Ah, const __hip_bfloat16* __restrict__ Al,
    const __hip_bfloat16* __restrict__ Bh, const __hip_bfloat16* __restrict__ Bl,
    float* __restrict__ outF, __hip_bfloat16* __restrict__ out16,
    const float* __restrict__ bias) {
  __shared__ __align__(16) char smem[49152];
  const int tid = threadIdx.x;
  const int lane = tid & 63, wid = tid >> 6;
  const int mh = wid >> 1, nh = wid & 1;

  int bx = blockIdx.x, by = blockIdx.y;
  if (MODE == 2) {
    int lid = by * 8 + bx;
    int xcd = lid & 7, k = lid >> 3;
    by = xcd * 32 + (k >> 3);
    bx = k & 7;
  }
  const int mBase = by * 128, nBase = bx * 64;

  f32x4 acc[4][2];
#pragma unroll
  for (int fm = 0; fm < 4; ++fm)
#pragma unroll
    for (int fn = 0; fn < 2; ++fn) acc[fm][fn] = (f32x4){0.f, 0.f, 0.f, 0.f};

  tile128x64(Ah + (size_t)mBase * 512, Al + (size_t)mBase * 512,
             Bh + (size_t)nBase * 512, Bl + (size_t)nBase * 512, smem, tid, acc);

#pragma unroll
  for (int fm = 0; fm < 4; ++fm)
#pragma unroll
    for (int fn = 0; fn < 2; ++fn)
#pragma unroll
      for (int r = 0; r < 4; ++r) {
        int row = mBase + mh * 64 + fm * 16 + (lane >> 4) * 4 + r;
        int col = nBase + nh * 32 + fn * 16 + (lane & 15);
        float v = acc[fm][fn][r];
        if (MODE == 2) {
          out16[(size_t)row * 512 + col] = __float2bfloat16(v);
        } else {
          int bb = row & 511, ss = row >> 9;   // A row = s*512 + b
          if (col < 96)
            outF[((size_t)bb * NSTEP + ss) * 96 + col] = v + bias[col];
        }
      }
}

// ---------------------------------------------------------------------------
// Persistent decode loop. 256 blocks x 512 threads.
// ---------------------------------------------------------------------------
struct DecodeArgs {
  const __hip_bfloat16 *W2h, *W2l;   // [2560][512]: rows<512 = Wh, >=512 = rec
  const __hip_bfloat16 *K1h, *K1l;   // [2048][512]
  const __hip_bfloat16 *Hp16, *bAh;  // [B*T][512]
  const float *bh, *Ws, *lstm_bias, *lstm_kernel;
  const int* text;
  float *qf;                          // [512][512] q (fp32, coherent)
  float *cstate;                      // [512][512] plain (block-local)
  float *hbuf;                        // [2][512*512] fp32 ping-pong (coherent)
  float *ctxf;                        // [512*512] fp32 (coherent)
  __hip_bfloat16 *hsh, *hsl;          // [27][512*512] pairs (for probs, plain)
  unsigned* flags;                    // 8 shards x 32 rank flags
};

__global__ __launch_bounds__(512) void decode_loop(DecodeArgs a) {
  __shared__ __align__(16) char smem[49152];
  const int tid = threadIdx.x;
  const int lane = tid & 63, wid = tid >> 6;
  const int shard = blockIdx.x & 7;
  const int rank = blockIdx.x >> 3;     // 0..31
  const int rbase = shard * 64;
  unsigned* flags = a.flags + shard * 32;
  unsigned target = 0;
  const int wm = wid >> 1, wn = wid & 1;  // 4x2 waves over 64x64 tile

  for (int s = 0; s < NSTEP; ++s) {
    const float* hcur = a.hbuf + (size_t)(s & 1) * 262144;
    float* hnxt = a.hbuf + (size_t)((s & 1) ^ 1) * 262144;

    // ---- SP1: q[64 rows][512] = h @ Wh. 8 tiles of 64x64 -> ranks 0..7.
    if (rank < 8) {
      __hip_bfloat16* sAh = (__hip_bfloat16*)smem;   // 8 KB
      __hip_bfloat16* sAl = sAh + 64 * 64;           // 8 KB
      __hip_bfloat16* sBh = sAl + 64 * 64;           // 8 KB
      __hip_bfloat16* sBl = sBh + 64 * 64;           // 8 KB
      f32x4 acc[2];
      acc[0] = (f32x4){0.f, 0.f, 0.f, 0.f};
      acc[1] = (f32x4){0.f, 0.f, 0.f, 0.f};
      for (int kt = 0; kt < 8; ++kt) {
        {  // A: h 64 rows x 64 k via 8B coherent loads -> split
          int row = tid >> 3, ch = tid & 7;
          const float* src = hcur + (size_t)(rbase + row) * 512 + kt * 64 + ch * 8;
          union { int4 q; __hip_bfloat16 h[8]; } uh, ul;
#pragma unroll
          for (int j2 = 0; j2 < 4; ++j2) {
            float2 v = cohL2(src + j2 * 2);
            split2(v.x, uh.h[j2 * 2], ul.h[j2 * 2]);
            split2(v.y, uh.h[j2 * 2 + 1], ul.h[j2 * 2 + 1]);
          }
          int swz = ch ^ (row & 7);
          *(int4*)&sAh[row * 64 + swz * 8] = uh.q;
          *(int4*)&sAl[row * 64 + swz * 8] = ul.q;
        }
        {  // B: Wh cols rank*64 + lr (plain cacheable)
          int lr = tid >> 3, ch = tid & 7;
          int swz = ch ^ (lr & 7);
          size_t g = (size_t)(rank * 64 + lr) * 512 + kt * 64 + ch * 8;
          *(int4*)&sBh[lr * 64 + swz * 8] = *(const int4*)&a.W2h[g];
          *(int4*)&sBl[lr * 64 + swz * 8] = *(const int4*)&a.W2l[g];
        }
        __syncthreads();
#pragma unroll
        for (int kk = 0; kk < 2; ++kk) {
          bf16x8 ahi, alo, bhi[2], blo[2];
          {
            int row = wm * 16 + (lane & 15);
            int ch = kk * 4 + (lane >> 4);
            int swz = ch ^ (row & 7);
            ahi = *(const bf16x8*)&sAh[row * 64 + swz * 8];
            alo = *(const bf16x8*)&sAl[row * 64 + swz * 8];
          }
#pragma unroll
          for (int fn = 0; fn < 2; ++fn) {
            int lr = wn * 32 + fn * 16 + (lane & 15);
            int ch = kk * 4 + (lane >> 4);
            int swz = ch ^ (lr & 7);
            bhi[fn] = *(const bf16x8*)&sBh[lr * 64 + swz * 8];
            blo[fn] = *(const bf16x8*)&sBl[lr * 64 + swz * 8];
          }
#pragma unroll
          for (int fn = 0; fn < 2; ++fn) {
            acc[fn] = __builtin_amdgcn_mfma_f32_16x16x32_bf16(ahi, bhi[fn], acc[fn], 0, 0, 0);
            acc[fn] = __builtin_amdgcn_mfma_f32_16x16x32_bf16(ahi, blo[fn], acc[fn], 0, 0, 0);
            acc[fn] = __builtin_amdgcn_mfma_f32_16x16x32_bf16(alo, bhi[fn], acc[fn], 0, 0, 0);
          }
        }
        __syncthreads();
      }
#pragma unroll
      for (int fn = 0; fn < 2; ++fn)
#pragma unroll
        for (int r = 0; r < 4; ++r) {
          int row = wm * 16 + (lane >> 4) * 4 + r;
          int col = rank * 64 + wn * 32 + fn * 16 + (lane & 15);
          cohS(&a.qf[(size_t)(rbase + row) * 512 + col], acc[fn][r]);
        }
    }
    target += 1;
    shard_sync(flags, rank, target, tid);

    // ---- SP2: attention, rows rbase + rank*2 + {0,1} in parallel halves.
    {
      const int half = tid >> 8, ltid = tid & 255, w4 = wid & 3;
      const int b = rbase + rank * 2 + half;
      float* es = (float*)smem;     // [2][64]
      float* als = es + 128;        // [2][64]

      float qv[8], wv[8];
      {
        const float* qp = a.qf + (size_t)b * 512 + lane * 8;
        const float* bp = a.bh + lane * 8;
        const float* wp = a.Ws + lane * 8;
        float4 h0 = *(const float4*)bp, h1 = *(const float4*)(bp + 4);
        float4 w0 = *(const float4*)wp, w1 = *(const float4*)(wp + 4);
        float2 q0 = cohL2(qp + 0), q1 = cohL2(qp + 2);
        float2 q2 = cohL2(qp + 4), q3 = cohL2(qp + 6);
        qv[0] = q0.x + h0.x; qv[1] = q0.y + h0.y;
        qv[2] = q1.x + h0.z; qv[3] = q1.y + h0.w;
        qv[4] = q2.x + h1.x; qv[5] = q2.y + h1.y;
        qv[6] = q3.x + h1.z; qv[7] = q3.y + h1.w;
        wv[0] = w0.x; wv[1] = w0.y; wv[2] = w0.z; wv[3] = w0.w;
        wv[4] = w1.x; wv[5] = w1.y; wv[6] = w1.z; wv[7] = w1.w;
      }
      const __hip_bfloat16* Hp = a.Hp16 + (size_t)b * 32768;
#pragma unroll
      for (int i = 0; i < 16; ++i) {
        int t = w4 * 16 + i;
        uint4 p = *(const uint4*)(Hp + (size_t)t * 512 + lane * 8);
        float sum = wv[0] * tanh_fast(bflo(p.x) + qv[0]) + wv[1] * tanh_fast(bfhi(p.x) + qv[1]) +
                    wv[2] * tanh_fast(bflo(p.y) + qv[2]) + wv[3] * tanh_fast(bfhi(p.y) + qv[3]) +
                    wv[4] * tanh_fast(bflo(p.z) + qv[4]) + wv[5] * tanh_fast(bfhi(p.z) + qv[5]) +
                    wv[6] * tanh_fast(bflo(p.w) + qv[6]) + wv[7] * tanh_fast(bfhi(p.w) + qv[7]);
#pragma unroll
        for (int off = 32; off; off >>= 1) sum += __shfl_xor(sum, off);
        if (lane == 0) es[half * 64 + t] = sum;
      }
      __syncthreads();
      if (w4 == 0) {
        float e = es[half * 64 + lane];
        float m = e;
#pragma unroll
        for (int off = 32; off; off >>= 1) m = fmaxf(m, __shfl_xor(m, off));
        float p = __expf(e - m);
        float sm = p;
#pragma unroll
        for (int off = 32; off; off >>= 1) sm += __shfl_xor(sm, off);
        als[half * 64 + lane] = p / sm;
      }
      __syncthreads();
      const unsigned* Bp = (const unsigned*)(a.bAh + (size_t)b * 32768);
      float sx = 0.f, sy = 0.f;
#pragma unroll 8
      for (int t = 0; t < 64; ++t) {
        unsigned u = Bp[t * 256 + ltid];
        float al = als[half * 64 + t];
        sx += al * bflo(u);
        sy += al * bfhi(u);
      }
      cohS2(&a.ctxf[(size_t)b * 512 + ltid * 2], sx, sy);
    }
    target += 1;
    shard_sync(flags, rank, target, tid);

    // ---- SP3: z[64 rows][64 gate-strided cols] = [ctx|h] @ [K1|W2rec],
    // K=1024 (16 kt), + fused LSTM pointwise. rank -> j-chunk of 16.
    {
      const int j0 = rank * 16;
      __hip_bfloat16* sAh = (__hip_bfloat16*)smem;   // 8 KB
      __hip_bfloat16* sAl = sAh + 64 * 64;           // 8 KB
      __hip_bfloat16* sBh = sAl + 64 * 64;           // 8 KB
      __hip_bfloat16* sBl = sBh + 64 * 64;           // 8 KB
      float* zl = (float*)(smem + 32768);            // 16 KB [64][64]

      f32x4 acc[2];
      acc[0] = (f32x4){0.f, 0.f, 0.f, 0.f};
      acc[1] = (f32x4){0.f, 0.f, 0.f, 0.f};
      for (int kt = 0; kt < 16; ++kt) {
        {  // A: kt<8 -> ctx, kt>=8 -> h (8B coherent -> split)
          int row = tid >> 3, ch = tid & 7;
          const float* src = (kt < 8)
            ? a.ctxf + (size_t)(rbase + row) * 512 + kt * 64 + ch * 8
            : hcur + (size_t)(rbase + row) * 512 + (kt - 8) * 64 + ch * 8;
          union { int4 q; __hip_bfloat16 h[8]; } uh, ul;
#pragma unroll
          for (int j2 = 0; j2 < 4; ++j2) {
            float2 v = cohL2(src + j2 * 2);
            split2(v.x, uh.h[j2 * 2], ul.h[j2 * 2]);
            split2(v.y, uh.h[j2 * 2 + 1], ul.h[j2 * 2 + 1]);
          }
          int swz = ch ^ (row & 7);
          *(int4*)&sAh[row * 64 + swz * 8] = uh.q;
          *(int4*)&sAl[row * 64 + swz * 8] = ul.q;
        }
        {  // B: local row lr = gate(4) x jj(16); kt<8 K1, kt>=8 W2rec
          int lr = tid >> 3, ch = tid & 7;
          int gate = lr >> 4, jj = lr & 15;
          int col = gate * 512 + j0 + jj;
          const __hip_bfloat16 *Bh0, *Bl0;
          size_t g;
          if (kt < 8) {
            g = (size_t)col * 512 + kt * 64 + ch * 8;
            Bh0 = a.K1h; Bl0 = a.K1l;
          } else {
            g = (size_t)(512 + col) * 512 + (kt - 8) * 64 + ch * 8;
            Bh0 = a.W2h; Bl0 = a.W2l;
          }
          int swz = ch ^ (lr & 7);
          *(int4*)&sBh[lr * 64 + swz * 8] = *(const int4*)&Bh0[g];
          *(int4*)&sBl[lr * 64 + swz * 8] = *(const int4*)&Bl0[g];
        }
        __syncthreads();
#pragma unroll
        for (int kk = 0; kk < 2; ++kk) {
          bf16x8 ahi, alo, bhi[2], blo[2];
          {
            int row = wm * 16 + (lane & 15);
            int ch = kk * 4 + (lane >> 4);
            int swz = ch ^ (row & 7);
            ahi = *(const bf16x8*)&sAh[row * 64 + swz * 8];
            alo = *(const bf16x8*)&sAl[row * 64 + swz * 8];
          }
#pragma unroll
          for (int fn = 0; fn < 2; ++fn) {
            int lr = wn * 32 + fn * 16 + (lane & 15);
            int ch = kk * 4 + (lane >> 4);
            int swz = ch ^ (lr & 7);
            bhi[fn] = *(const bf16x8*)&sBh[lr * 64 + swz * 8];
            blo[fn] = *(const bf16x8*)&sBl[lr * 64 + swz * 8];
          }
#pragma unroll
          for (int fn = 0; fn < 2; ++fn) {
            acc[fn] = __builtin_amdgcn_mfma_f32_16x16x32_bf16(ahi, bhi[fn], acc[fn], 0, 0, 0);
            acc[fn] = __builtin_amdgcn_mfma_f32_16x16x32_bf16(ahi, blo[fn], acc[fn], 0, 0, 0);
            acc[fn] = __builtin_amdgcn_mfma_f32_16x16x32_bf16(alo, bhi[fn], acc[fn], 0, 0, 0);
          }
        }
        __syncthreads();
      }
      // z (= ctx@K1 + h@rec) -> LDS
#pragma unroll
      for (int fn = 0; fn < 2; ++fn)
#pragma unroll
        for (int r = 0; r < 4; ++r) {
          int row = wm * 16 + (lane >> 4) * 4 + r;
          int col = wn * 32 + fn * 16 + (lane & 15);
          zl[row * 64 + col] = acc[fn][r];
        }
      __syncthreads();

      // LSTM pointwise: thread -> (row, two adjacent j)
      {
        int row = tid >> 3, j = (tid & 7) * 2;
        int b = rbase + row;
        int jc = j0 + j;
        int chr = a.text[b * NSTEP + s];
        const float* crow = a.lstm_kernel + (size_t)(512 + chr) * 2048;
        float hv[2];
#pragma unroll
        for (int u = 0; u < 2; ++u) {
          float g4[4];
#pragma unroll
          for (int g = 0; g < 4; ++g) {
            int col = g * 512 + jc + u;
            g4[g] = zl[row * 64 + g * 16 + j + u] + a.lstm_bias[col] + crow[col];
          }
          float iv = sigmoid_fast(g4[0]);
          float fv = sigmoid_fast(g4[1]);
          float gv = tanh_fast(g4[2]);
          float ov = sigmoid_fast(g4[3]);
          size_t gi = (size_t)b * 512 + jc + u;
          float c = fv * a.cstate[gi] + iv * gv;   // block-local across steps
          a.cstate[gi] = c;
          hv[u] = ov * tanh_fast(c);
        }
        size_t gi0 = (size_t)b * 512 + jc;
        cohS2(&hnxt[gi0], hv[0], hv[1]);
        __hip_bfloat16 h0, l0, h1, l1;
        split2(hv[0], h0, l0);
        split2(hv[1], h1, l1);
        union { __hip_bfloat16 h[2]; unsigned u; } ph, pl;
        ph.h[0] = h0; ph.h[1] = h1;
        pl.h[0] = l0; pl.h[1] = l1;
        ((unsigned*)a.hsh)[((size_t)(s + 1) * 262144 + gi0) >> 1] = ph.u;
        ((unsigned*)a.hsl)[((size_t)(s + 1) * 262144 + gi0) >> 1] = pl.u;
      }
    }
    target += 1;
    shard_sync(flags, rank, target, tid);
  }
}

// ---------------------------------------------------------------------------
extern "C" void kernel_launch(void* const* d_in, const int* in_sizes, int n_in,
                              void* d_out, int out_size, void* d_ws, size_t ws_size,
                              hipStream_t stream) {
  (void)in_sizes; (void)n_in; (void)out_size; (void)ws_size;
  const float* batch_H = (const float*)d_in[0];
  const int* text = (const int*)d_in[1];
  const float* Wi = (const float*)d_in[3];
  const float* Wh = (const float*)d_in[4];
  const float* bh = (const float*)d_in[5];
  const float* Ws = (const float*)d_in[6];
  const float* lstm_kernel = (const float*)d_in[7];
  const float* lstm_rec = (const float*)d_in[8];
  const float* lstm_bias = (const float*)d_in[9];
  const float* Wgen = (const float*)d_in[10];
  const float* bgen = (const float*)d_in[11];
  float* out = (float*)d_out;

  char* w = (char*)d_ws;
  auto alloc = [&](size_t bytes) {
    char* p = w;
    w += (bytes + 255) & ~(size_t)255;
    return p;
  };
  const size_t NE = 32768ull * 512;
  __hip_bfloat16* bAh = (__hip_bfloat16*)alloc(NE * 2);
  char* bAl_region = alloc(NE * 2);   // dead after Hproj; reused below
  __hip_bfloat16* bAl = (__hip_bfloat16*)bAl_region;
  __hip_bfloat16* Hp16 = (__hip_bfloat16*)alloc(NE * 2);
  __hip_bfloat16* WiT_h = (__hip_bfloat16*)alloc(512ull * 512 * 2);
  __hip_bfloat16* WiT_l = (__hip_bfloat16*)alloc(512ull * 512 * 2);
  __hip_bfloat16* W2T_h = (__hip_bfloat16*)alloc(2560ull * 512 * 2);
  __hip_bfloat16* W2T_l = (__hip_bfloat16*)alloc(2560ull * 512 * 2);
  __hip_bfloat16* K1T_h = (__hip_bfloat16*)alloc(2048ull * 512 * 2);
  __hip_bfloat16* K1T_l = (__hip_bfloat16*)alloc(2048ull * 512 * 2);
  __hip_bfloat16* WgT_h = (__hip_bfloat16*)alloc(128ull * 512 * 2);
  __hip_bfloat16* WgT_l = (__hip_bfloat16*)alloc(128ull * 512 * 2);
  float* qf = (float*)alloc(512ull * 512 * 4);           // 1 MB
  float* cstate = (float*)alloc(512ull * 512 * 4);       // 1 MB
  unsigned* flags = (unsigned*)alloc(1024);              // 8 x 32 flags
  // Aliases inside the dead bAl region:
  __hip_bfloat16* hsh = (__hip_bfloat16*)bAl_region;                         // 14.16 MB
  __hip_bfloat16* hsl = (__hip_bfloat16*)(bAl_region + 27ull * 262144 * 2);  // 14.16 MB
  float* hbuf = (float*)(bAl_region + 2ull * 27 * 262144 * 2);               // 2 MB
  float* ctxf = (float*)(bAl_region + 2ull * 27 * 262144 * 2 + 2097152);     // 1 MB

  split_pair<<<dim3(8192), 256, 0, stream>>>(batch_H, bAh, bAl, (int)(NE / 8));
  dim3 tb(32, 8, 1);
  transpose_split<<<dim3(16, 16), tb, 0, stream>>>(Wi, 512, 512, Wi, 512, 512, WiT_h, WiT_l);
  transpose_split<<<dim3(80, 16), tb, 0, stream>>>(Wh, 512, 512, lstm_rec, 2048, 2560, W2T_h, W2T_l);
  transpose_split<<<dim3(64, 16), tb, 0, stream>>>(lstm_kernel, 2048, 2048, lstm_kernel, 2048, 2048, K1T_h, K1T_l);
  transpose_split<<<dim3(4, 16), tb, 0, stream>>>(Wgen, 96, 96, Wgen, 96, 96, WgT_h, WgT_l);

  gemm_pre<2><<<dim3(8, 256), 256, 0, stream>>>(bAh, bAl, WiT_h, WiT_l,
                                                nullptr, Hp16, nullptr);

  hipMemsetAsync(hbuf, 0, 262144ull * 4, stream);      // h_{-1} = 0 (slot 0)
  hipMemsetAsync(cstate, 0, 512ull * 512 * 4, stream);
  hipMemsetAsync(flags, 0, 1024, stream);

  DecodeArgs args;
  args.W2h = W2T_h; args.W2l = W2T_l;
  args.K1h = K1T_h; args.K1l = K1T_l;
  args.Hp16 = Hp16; args.bAh = bAh;
  args.bh = bh; args.Ws = Ws; args.lstm_bias = lstm_bias; args.lstm_kernel = lstm_kernel;
  args.text = text;
  args.qf = qf; args.cstate = cstate;
  args.hbuf = hbuf; args.ctxf = ctxf;
  args.hsh = hsh; args.hsl = hsl;
  args.flags = flags;
  decode_loop<<<dim3(NBLK), 512, 0, stream>>>(args);

  gemm_pre<1><<<dim3(2, 104), 256, 0, stream>>>(hsh + 262144, hsl + 262144,
                                                WgT_h, WgT_l, out, nullptr, bgen);
}